// Round 6
// baseline (695.916 us; speedup 1.0000x reference)
//
#include <hip/hip_runtime.h>
#include <math.h>

typedef unsigned short bfu;   // raw bf16 bits
typedef short bf16x8 __attribute__((ext_vector_type(8)));
typedef float f32x4 __attribute__((ext_vector_type(4)));

__device__ __forceinline__ float bs2f(bfu s){
  union{ unsigned int u; float f; } v; v.u = ((unsigned int)s) << 16; return v.f;
}
__device__ __forceinline__ bfu f2bs(float f){
  union{ float ff; unsigned int u; } v; v.ff = f;
  unsigned int u = v.u;
  unsigned int r = (u + 0x7fffu + ((u >> 16) & 1u)) >> 16;   // RNE
  return (bfu)r;
}

struct LevelTab { int twoff[13]; int ll[13]; int logh[13]; };
struct WPtrs { const void* p[6]; };

// ---------------- dtype sniff ------------------------------------------------
__global__ __launch_bounds__(256) void k_sniff(const bfu* __restrict__ x, int* __restrict__ flag){
  __shared__ int cnt;
  if(threadIdx.x==0) cnt = 0;
  __syncthreads();
  int c = 0;
  for(int j=threadIdx.x; j<4096; j+=256){
    bfu v = x[2*j];
    int e = (v>>7)&0xFF;
    if(e >= 0xC0) c++;
  }
  atomicAdd(&cnt, c);
  __syncthreads();
  if(threadIdx.x==0) flag[0] = (cnt > 64) ? 1 : 0;
}

// ---------------- small arrays -> bf16. 0=ec_s,128=ec_d,256=rc_e,384=rc_o,512=ln_w,640=ln_b
__global__ __launch_bounds__(256) void k_cvt_small(
    const void* lnw, const void* lnb, const void* ecs, const void* ecd,
    const void* rce, const void* rco, bfu* __restrict__ CSM, const int* __restrict__ FLAG){
  int f32 = FLAG[0];
  const void* src[6] = {ecs, ecd, rce, rco, lnw, lnb};
  int tid = threadIdx.x;
  for(int a=0; a<6; ++a)
    for(int j=tid; j<128; j+=256)
      CSM[a*128+j] = f32 ? f2bs(((const float*)src[a])[j]) : ((const bfu*)src[a])[j];
}

// ---------------- weight transpose: W[i][o][f] -> W2[w][f][o][i], bf16 -------
__global__ __launch_bounds__(256) void k_wtrans(WPtrs wp, bfu* __restrict__ W2, const int* __restrict__ FLAG){
  int f32 = FLAG[0];
  int o = blockIdx.x;          // 0..127
  int w = blockIdx.y;          // 0..5
  __shared__ bfu tile[64][130];   // [f][i]
  int tid = threadIdx.x;
  const void* src = wp.p[w];
  if(f32){
    const float* s = (const float*)src;
    #pragma unroll
    for(int it=0; it<8; ++it){
      int e = it*256 + tid;
      int i = e >> 4, fq = e & 15;
      float4 v = *reinterpret_cast<const float4*>(s + ((size_t)i*128 + o)*64 + fq*4);
      tile[fq*4+0][i] = f2bs(v.x);
      tile[fq*4+1][i] = f2bs(v.y);
      tile[fq*4+2][i] = f2bs(v.z);
      tile[fq*4+3][i] = f2bs(v.w);
    }
  } else {
    const bfu* s = (const bfu*)src;
    #pragma unroll
    for(int it=0; it<4; ++it){
      int e = it*256 + tid;
      int i = e >> 3, fq = e & 7;
      union{uint4 u; bfu x[8];} U;
      U.u = *reinterpret_cast<const uint4*>(s + ((size_t)i*128 + o)*64 + fq*8);
      #pragma unroll
      for(int j=0;j<8;++j) tile[fq*8+j][i] = U.x[j];
    }
  }
  __syncthreads();
  bfu* dst = W2 + (size_t)w*64*128*128 + (size_t)o*128;
  #pragma unroll
  for(int it=0; it<8; ++it){
    int e = it*256 + tid;
    int f = e >> 5, iq = e & 31;
    union{uint2 u; bfu x[4];} P;
    #pragma unroll
    for(int j=0;j<4;++j) P.x[j] = tile[f][iq*4+j];
    *reinterpret_cast<uint2*>(dst + (size_t)f*128*128 + iq*4) = P.u;
  }
}

// ---------------- bf16 twiddle matrices for MFMA levels 0..5 -----------------
__global__ __launch_bounds__(256) void k_twgenF(bfu* __restrict__ TWF, bfu* __restrict__ TWI){
  int e = blockIdx.x*256 + threadIdx.x;      // 0..1032191
  int kind = blockIdx.y;
  const int offs[7] = {0,524288,786432,917504,983040,1015808,1032192};
  int le = 5;
  #pragma unroll
  for(int i=0;i<6;++i){ if(e < offs[i+1]){ le = i; break; } }
  int rem = e - offs[le];
  int logh = 12 - le;
  int h = 1 << logh;
  int f, t, neg;
  if(kind==0){ int r = rem >> logh; t = rem & (h-1); f = (r<64)?r:(r-64); neg = (r>=64); }
  else       { t = rem >> 7; int f2 = rem & 127;     f = (f2<64)?f2:(f2-64); neg = (f2>=64); }
  int m = (f*t) & (h-1);
  float th = 6.283185307179586f * ((float)m / (float)h);
  float s, c; sincosf(th, &s, &c);
  float val = neg ? -s : c;
  if(kind==0) TWF[e] = f2bs(val); else TWI[e] = f2bs(val);
}

// ---------------- fp32 twiddles for deep levels ------------------------------
__global__ __launch_bounds__(256) void k_twgen(LevelTab lt, float* __restrict__ tw){
  int lev = blockIdx.y;
  int logh = lt.logh[lev];
  int h = 1 << logh;
  int l = lt.ll[lev];
  int tot = l*h;
  int idx = blockIdx.x*256 + threadIdx.x;
  if(idx >= tot) return;
  int t = idx & (h-1);
  int f = idx >> logh;
  int m = (f*t) & (h-1);
  float th = 6.283185307179586f * ((float)m / (float)h);
  float s, c; sincosf(th, &s, &c);
  tw[lt.twoff[lev] + idx] = c;
  tw[lt.twoff[lev] + tot + idx] = s;
}

// ---------------- level-0 decompose v3 ---------------------------------------
// grid (h/32, 16 b), block 256. Input LDS-staged (unique coalesced loads),
// output LDS-staged (coalesced 64B-run writes). LDS = 53.25 KB -> 3 blocks/CU.
__global__ __launch_bounds__(256) void k_decomp0(
    const void* __restrict__ xin, bfu* __restrict__ dT, bfu* __restrict__ sT,
    const bfu* __restrict__ CSM, int h, const int* __restrict__ FLAG)
{
  int f32 = FLAG[0];
  __shared__ float ls[64][132];
  __shared__ bfu sdo[128][36];
  __shared__ bfu sso[128][36];
  __shared__ float Fd[16][8], Fs[16][8];
  int tid = threadIdx.x;
  if(tid < 128){ Fs[tid>>3][tid&7] = bs2f(CSM[tid]); Fd[tid>>3][tid&7] = bs2f(CSM[128+tid]); }
  int b = blockIdx.y;
  int t0in = blockIdx.x * 64;       // 64 input rows -> 32 output t
  if(f32){
    const float* src = (const float*)xin + ((size_t)b*2*h + t0in)*128;
    #pragma unroll
    for(int it=0; it<8; ++it){
      int e = it*256 + tid;
      int row = e>>5, cq = e&31;
      float4 v = *reinterpret_cast<const float4*>(src + (size_t)row*128 + cq*4);
      ls[row][cq*4+0]=v.x; ls[row][cq*4+1]=v.y; ls[row][cq*4+2]=v.z; ls[row][cq*4+3]=v.w;
    }
  } else {
    const bfu* src = (const bfu*)xin + ((size_t)b*2*h + t0in)*128;
    #pragma unroll
    for(int it=0; it<4; ++it){
      int e = it*256 + tid;
      int row = e>>4, cq = e&15;
      union{uint4 u; bfu x[8];} U;
      U.u = *reinterpret_cast<const uint4*>(src + (size_t)row*128 + cq*8);
      #pragma unroll
      for(int j=0;j<8;++j) ls[row][cq*8+j] = bs2f(U.x[j]);
    }
  }
  __syncthreads();
  int g = tid>>7, ch = tid&127;
  int c = ch>>3, kp = ch&7;
  float fdE[8], fdO[8], fsE[8], fsO[8];
  #pragma unroll
  for(int j=0;j<8;++j){ fdE[j]=Fd[j][kp]; fdO[j]=Fd[8+j][kp]; fsE[j]=Fs[j][kp]; fsO[j]=Fs[8+j][kp]; }
  union{ uint2 u; bfu x[4]; } Dq, Sq;
  #pragma unroll
  for(int tl=0; tl<16; ++tl){
    int rl = 2*(g*16+tl);
    const float* ev = &ls[rl][c*8];
    const float* od = &ls[rl+1][c*8];
    float d=0.f, s=0.f;
    #pragma unroll
    for(int j=0;j<8;++j){
      d += ev[j]*fdE[j] + od[j]*fdO[j];
      s += ev[j]*fsE[j] + od[j]*fsO[j];
    }
    Dq.x[tl&3] = f2bs(d); Sq.x[tl&3] = f2bs(s);
    if((tl&3)==3){
      int tb = g*16 + (tl & ~3);
      *reinterpret_cast<uint2*>(&sdo[ch][tb]) = Dq.u;
      *reinterpret_cast<uint2*>(&sso[ch][tb]) = Sq.u;
    }
  }
  __syncthreads();
  size_t obase = (size_t)b*128*h + (t0in>>1);
  #pragma unroll
  for(int it=0; it<4; ++it){
    int e = it*256 + tid;            // 1024 uint2 slots: 128 rows x 8 quads
    int r = e >> 3, kq = e & 7;
    union{uint2 u; bfu x[4];} P;
    #pragma unroll
    for(int j=0;j<4;++j) P.x[j] = sdo[r][kq*4+j];
    *reinterpret_cast<uint2*>(dT + obase + (size_t)r*h + kq*4) = P.u;
  }
  #pragma unroll
  for(int it=0; it<4; ++it){
    int e = it*256 + tid;
    int r = e >> 3, kq = e & 7;
    union{uint2 u; bfu x[4];} P;
    #pragma unroll
    for(int j=0;j<4;++j) P.x[j] = sso[r][kq*4+j];
    *reinterpret_cast<uint2*>(sT + obase + (size_t)r*h + kq*4) = P.u;
  }
}

// ---------------- transposed decompose, big levels (h >= 256) ----------------
__global__ __launch_bounds__(256) void k_decompT_big(
    const bfu* __restrict__ inT, bfu* __restrict__ dT, bfu* __restrict__ sT,
    const bfu* __restrict__ CSM, int h)
{
  __shared__ float Fd[16][8], Fs[16][8];
  int tid = threadIdx.x;
  if(tid < 128){ Fs[tid>>3][tid&7] = bs2f(CSM[tid]); Fd[tid>>3][tid&7] = bs2f(CSM[128+tid]); }
  __syncthreads();
  int tt0 = blockIdx.x * 256;
  int b = blockIdx.y, c = blockIdx.z;
  int kp = tid >> 5, tq = tid & 31;
  float fdE[8], fdO[8], fsE[8], fsO[8];
  #pragma unroll
  for(int k=0;k<8;++k){ fdE[k]=Fd[k][kp]; fdO[k]=Fd[8+k][kp]; fsE[k]=Fs[k][kp]; fsO[k]=Fs[8+k][kp]; }
  const bfu* base = inT + ((size_t)b*128 + c*8)*(size_t)(2*h) + (size_t)2*tt0 + tq*16;
  union{uint4 u[2]; bfu x[16];} E[8];
  #pragma unroll
  for(int k=0;k<8;++k){
    E[k].u[0] = *reinterpret_cast<const uint4*>(base + (size_t)k*(2*h));
    E[k].u[1] = *reinterpret_cast<const uint4*>(base + (size_t)k*(2*h) + 8);
  }
  union{uint4 u; bfu x[8];} Od, Os;
  #pragma unroll
  for(int to=0; to<8; ++to){
    float d=0.f, s=0.f;
    #pragma unroll
    for(int k=0;k<8;++k){
      float ev = bs2f(E[k].x[2*to]), od = bs2f(E[k].x[2*to+1]);
      d += ev*fdE[k] + od*fdO[k];
      s += ev*fsE[k] + od*fsO[k];
    }
    Od.x[to] = f2bs(d); Os.x[to] = f2bs(s);
  }
  size_t ob = ((size_t)b*128 + c*8 + kp)*h + tt0 + tq*8;
  *reinterpret_cast<uint4*>(dT + ob) = Od.u;
  *reinterpret_cast<uint4*>(sT + ob) = Os.u;
}

// ---------------- transposed decompose (small levels) ------------------------
__global__ __launch_bounds__(256) void k_decompT(
    const bfu* __restrict__ inT, bfu* __restrict__ dT, bfu* __restrict__ sT,
    const bfu* __restrict__ CSM, int h, int total)
{
  __shared__ float Fd[16][8], Fs[16][8];
  int tid = threadIdx.x;
  if(tid < 128){ Fs[tid>>3][tid&7] = bs2f(CSM[tid]); Fd[tid>>3][tid&7] = bs2f(CSM[128+tid]); }
  __syncthreads();
  int idx = blockIdx.x*256 + tid;
  if(idx >= total) return;
  if(h >= 4){
    int nto = h>>2;
    int to = idx & (nto-1);
    int bc = idx / nto;
    int c = bc & 15, b = bc >> 4;
    const bfu* base = inT + ((size_t)b*128 + c*8)*(size_t)(2*h) + to*8;
    float d8[4][8] = {}, s8[4][8] = {};
    #pragma unroll
    for(int k=0;k<8;++k){
      union{uint4 u; bfu x[8];} U;
      U.u = *reinterpret_cast<const uint4*>(base + (size_t)k*(2*h));
      const float* fdE = Fd[k]; const float* fdO = Fd[8+k];
      const float* fsE = Fs[k]; const float* fsO = Fs[8+k];
      #pragma unroll
      for(int tl=0; tl<4; ++tl){
        float ev = bs2f(U.x[2*tl]), od = bs2f(U.x[2*tl+1]);
        #pragma unroll
        for(int kp=0;kp<8;++kp){
          d8[tl][kp] += ev*fdE[kp] + od*fdO[kp];
          s8[tl][kp] += ev*fsE[kp] + od*fsO[kp];
        }
      }
    }
    #pragma unroll
    for(int kp=0;kp<8;++kp){
      union{uint2 u; bfu x[4];} Od, Os;
      #pragma unroll
      for(int tl=0;tl<4;++tl){ Od.x[tl]=f2bs(d8[tl][kp]); Os.x[tl]=f2bs(s8[tl][kp]); }
      size_t ob = ((size_t)b*128 + c*8 + kp)*h + to*4;
      *reinterpret_cast<uint2*>(dT + ob) = Od.u;
      *reinterpret_cast<uint2*>(sT + ob) = Os.u;
    }
  } else {
    int c = idx & 15, b = idx >> 4;
    const bfu* base = inT + ((size_t)b*128 + c*8)*(size_t)(2*h);
    for(int tl=0; tl<h; ++tl){
      float d8[8]={}, s8[8]={};
      for(int k=0;k<8;++k){
        float ev = bs2f(base[(size_t)k*2*h + 2*tl]);
        float od = bs2f(base[(size_t)k*2*h + 2*tl+1]);
        #pragma unroll
        for(int kp=0;kp<8;++kp){
          d8[kp] += ev*Fd[k][kp] + od*Fd[8+k][kp];
          s8[kp] += ev*Fs[k][kp] + od*Fs[8+k][kp];
        }
      }
      for(int kp=0;kp<8;++kp){
        size_t ob = ((size_t)b*128 + c*8 + kp)*h + tl;
        dT[ob] = f2bs(d8[kp]); sT[ob] = f2bs(s8[kp]);
      }
    }
  }
}

// ---------------- MFMA forward DFT -------------------------------------------
// grid (np, 16 b, 4): z = sig*2 + rh. Block computes rows [rh*64, rh*64+64)
// x 128 ch of FTP[p][sig][b], K range [p*Kpart, (p+1)*Kpart).
__global__ __launch_bounds__(256) void k_fwdft_mfma(
    const bfu* __restrict__ dT, const bfu* __restrict__ sT,
    const bfu* __restrict__ TWFl, float* __restrict__ FTP,
    int h, int Kpart)
{
  int p = blockIdx.x, b = blockIdx.y;
  int sig = blockIdx.z >> 1, rh = blockIdx.z & 1;
  const bfu* SIG = (sig ? sT : dT) + (size_t)b*128*h;
  const bfu* TWr = TWFl + (size_t)(rh*64)*h;
  __shared__ bfu lsA[64*72];
  __shared__ bfu lsB[128*72];
  int tid = threadIdx.x;
  int wave = tid>>6, lane = tid&63;
  int mh = (wave>>1)*32, nh = (wave&1)*64;
  int ml = lane&15, q = lane>>4;
  f32x4 acc[2][4];
  #pragma unroll
  for(int i=0;i<2;++i){
    #pragma unroll
    for(int j=0;j<4;++j) acc[i][j] = (f32x4)0.f;
  }
  int k0base = p*Kpart;
  for(int kc=0; kc<Kpart; kc+=64){
    int k0 = k0base + kc;
    #pragma unroll
    for(int it=0; it<2; ++it){
      int slot = it*256 + tid;        // 512 uint4: 64 rows x 8 kq
      int row = slot>>3, kq = slot&7;
      *reinterpret_cast<uint4*>(&lsA[row*72 + kq*8]) =
        *reinterpret_cast<const uint4*>(&TWr[(size_t)row*h + k0 + kq*8]);
    }
    #pragma unroll
    for(int it=0; it<4; ++it){
      int slot = it*256 + tid;        // 1024 uint4: 128 rows x 8 kq
      int row = slot>>3, kq = slot&7;
      *reinterpret_cast<uint4*>(&lsB[row*72 + kq*8]) =
        *reinterpret_cast<const uint4*>(&SIG[(size_t)row*h + k0 + kq*8]);
    }
    __syncthreads();
    #pragma unroll
    for(int kk=0; kk<64; kk+=32){
      bf16x8 af[2], bfr[4];
      #pragma unroll
      for(int mi=0;mi<2;++mi)
        af[mi] = *reinterpret_cast<const bf16x8*>(&lsA[(mh+mi*16+ml)*72 + kk + q*8]);
      #pragma unroll
      for(int ni=0;ni<4;++ni)
        bfr[ni] = *reinterpret_cast<const bf16x8*>(&lsB[(nh+ni*16+ml)*72 + kk + q*8]);
      #pragma unroll
      for(int mi=0;mi<2;++mi){
        #pragma unroll
        for(int ni=0;ni<4;++ni)
          acc[mi][ni] = __builtin_amdgcn_mfma_f32_16x16x32_bf16(af[mi], bfr[ni], acc[mi][ni], 0,0,0);
      }
    }
    __syncthreads();
  }
  float* dst = FTP + (((size_t)p*2 + sig)*16 + b)*128*128;
  #pragma unroll
  for(int mi=0;mi<2;++mi){
    #pragma unroll
    for(int ni=0;ni<4;++ni){
      int row = rh*64 + mh + mi*16 + q*4;
      int col = nh + ni*16 + ml;
      #pragma unroll
      for(int r=0;r<4;++r)
        dst[(size_t)(row+r)*128 + col] = acc[mi][ni][r];
    }
  }
}

// ---------------- deep forward DFT, LDS-resident -----------------------------
__global__ __launch_bounds__(256) void k_fwdeep2(
    const bfu* __restrict__ dT, const bfu* __restrict__ sT,
    float* __restrict__ FTP, const float* __restrict__ TWc,
    int h, int l, int logh)
{
  int b = blockIdx.x, sig = blockIdx.y;
  const bfu* src = (sig? sT : dT) + (size_t)b*128*h;
  float* dst = FTP + ((size_t)sig*16 + b)*128*128;
  __shared__ float s_sig[128*65];
  __shared__ float s_twc[33*64];
  __shared__ float s_tws[33*64];
  int tid = threadIdx.x;
  int hp = h + 1;
  for(int e = tid; e < 128*h; e += 256){
    int ch = e >> logh, t = e & (h-1);
    s_sig[ch*hp + t] = bs2f(src[e]);
  }
  int lh = l*h;
  const float* TWs = TWc + (size_t)lh;
  for(int e = tid; e < lh; e += 256){ s_twc[e] = TWc[e]; s_tws[e] = TWs[e]; }
  __syncthreads();
  for(int idx = tid; idx < l*128; idx += 256){
    int f = idx >> 7, ch = idx & 127;
    const float* sp = &s_sig[ch*hp];
    const float* cp = &s_twc[f*h];
    const float* zp = &s_tws[f*h];
    float re = 0.f, im = 0.f;
    for(int t=0; t<h; ++t){ float v = sp[t]; re += v*cp[t]; im -= v*zp[t]; }
    dst[(size_t)f*128 + ch] = re;
    dst[(size_t)(64+f)*128 + ch] = im;
  }
}

// ---------------- FTP reduce + A-matrix build (bf16) -------------------------
__global__ __launch_bounds__(256) void k_ftpred(
    const float* __restrict__ FTP, bfu* __restrict__ XA, int np, int lmax)
{
  int e = blockIdx.x*256 + threadIdx.x;     // 0..131071
  const size_t PS = (size_t)2*16*128*128;
  int ch4 = e & 31;
  int row = (e>>5) & 127;
  int b   = (e>>12) & 15;
  int sig = e>>16;
  int f = row & 63, im = row >> 6;
  if(f >= lmax) return;
  size_t src = (((size_t)sig*16 + b)*128 + row)*128 + (size_t)ch4*4;
  f32x4 v = *reinterpret_cast<const f32x4*>(&FTP[src]);
  for(int p=1;p<np;++p)
    v += *reinterpret_cast<const f32x4*>(&FTP[src + (size_t)p*PS]);
  int ch = ch4*4;
  union{ uint2 u; bfu x[4]; } P1, P3;
  #pragma unroll
  for(int j=0;j<4;++j){
    float vj = v[j];
    P1.x[j] = f2bs(im ? -vj : vj);
    P3.x[j] = f2bs(vj);
  }
  size_t base = (size_t)f*32*512;
  *reinterpret_cast<uint2*>(&XA[base + (size_t)b*512 + sig*256 + im*128 + ch]) = P1.u;
  *reinterpret_cast<uint2*>(&XA[base + (size_t)(16+b)*512 + sig*256 + (1-im)*128 + ch]) = P3.u;
}

// ---------------- MFMA mode mixing: XA x W2 -> YT ----------------------------
__global__ __launch_bounds__(256) void k_modemix_mfma(
    const bfu* __restrict__ XA, const bfu* __restrict__ W2,
    bfu* __restrict__ YT, int h)
{
  int f = blockIdx.x;
  int obase = blockIdx.y * 16;
  int tid = threadIdx.x;
  int wid = tid>>6, lane = tid&63;
  int m = wid & 1, part = wid >> 1;
  int ml = lane & 15, q = lane >> 4;
  const size_t WSZ = (size_t)64*128*128;
  const bfu* Ab = XA + ((size_t)f*32 + m*16 + ml)*512 + q*8;
  const bfu* Wb = W2 + ((size_t)f*128 + obase + ml)*128 + q*8;
  f32x4 acc = (f32x4)0.f;
  if(part == 0){
    #pragma unroll
    for(int ks=0; ks<16; ++ks){
      bf16x8 A = *reinterpret_cast<const bf16x8*>(Ab + ks*32);
      bf16x8 B = *reinterpret_cast<const bf16x8*>(Wb + (size_t)(ks>>2)*WSZ + (ks&3)*32);
      acc = __builtin_amdgcn_mfma_f32_16x16x32_bf16(A, B, acc, 0,0,0);
    }
  } else {
    #pragma unroll
    for(int ks=0; ks<8; ++ks){
      bf16x8 A = *reinterpret_cast<const bf16x8*>(Ab + ks*32);
      bf16x8 B = *reinterpret_cast<const bf16x8*>(Wb + (size_t)(4 + (ks>>2))*WSZ + (ks&3)*32);
      acc = __builtin_amdgcn_mfma_f32_16x16x32_bf16(A, B, acc, 0,0,0);
    }
  }
  bool edge = (f==0) || (2*f == h);
  float sc = edge ? 1.0f/(float)h : 2.0f/(float)h;
  int fo = m ? (64+f) : f;
  int o = obase + ml;
  bfu* dst = YT + (part ? (size_t)16*128*128 : 0);
  #pragma unroll
  for(int r=0;r<4;++r){
    int b = q*4 + r;
    float val = acc[r]*sc;
    if(m && edge) val = 0.f;
    dst[((size_t)b*128 + o)*128 + fo] = f2bs(val);
  }
}

// ---------------- MFMA inverse DFT: Ud/Us [b][t][ch] bf16 --------------------
__global__ __launch_bounds__(256) void k_invdft_mfma(
    const bfu* __restrict__ YT, const bfu* __restrict__ TWIl,
    bfu* __restrict__ Ud, bfu* __restrict__ Us, int h)
{
  int bx = blockIdx.x, b = blockIdx.y, u = blockIdx.z;
  bfu* outp = u ? Us : Ud;
  const bfu* Y = YT + ((size_t)u*16 + b)*128*128;
  int t0 = bx*128;
  __shared__ bfu lsA[128*136];
  __shared__ bfu lsB[128*136];
  int tid = threadIdx.x;
  #pragma unroll
  for(int it=0; it<8; ++it){
    int slot = it*256 + tid;
    int row = slot>>4, kq = slot&15;
    *reinterpret_cast<uint4*>(&lsA[row*136 + kq*8]) =
      *reinterpret_cast<const uint4*>(&TWIl[(size_t)(t0+row)*128 + kq*8]);
    *reinterpret_cast<uint4*>(&lsB[row*136 + kq*8]) =
      *reinterpret_cast<const uint4*>(&Y[(size_t)row*128 + kq*8]);
  }
  __syncthreads();
  int wave = tid>>6, lane = tid&63;
  int mh = (wave>>1)*64, nh = (wave&1)*64;
  int ml = lane&15, q = lane>>4;
  f32x4 acc[4][4];
  #pragma unroll
  for(int i=0;i<4;++i){
    #pragma unroll
    for(int j=0;j<4;++j) acc[i][j] = (f32x4)0.f;
  }
  #pragma unroll
  for(int kk=0; kk<128; kk+=32){
    bf16x8 af[4], bfr[4];
    #pragma unroll
    for(int mi=0;mi<4;++mi)
      af[mi] = *reinterpret_cast<const bf16x8*>(&lsA[(mh+mi*16+ml)*136 + kk + q*8]);
    #pragma unroll
    for(int ni=0;ni<4;++ni)
      bfr[ni] = *reinterpret_cast<const bf16x8*>(&lsB[(nh+ni*16+ml)*136 + kk + q*8]);
    #pragma unroll
    for(int mi=0;mi<4;++mi){
      #pragma unroll
      for(int ni=0;ni<4;++ni)
        acc[mi][ni] = __builtin_amdgcn_mfma_f32_16x16x32_bf16(af[mi], bfr[ni], acc[mi][ni], 0,0,0);
    }
  }
  #pragma unroll
  for(int mi=0;mi<4;++mi){
    #pragma unroll
    for(int ni=0;ni<4;++ni){
      int row = mh + mi*16 + q*4;
      int col = nh + ni*16 + ml;
      #pragma unroll
      for(int r=0;r<4;++r)
        outp[((size_t)b*h + t0+row+r)*128 + col] = f2bs(acc[mi][ni][r]);
    }
  }
}

// ---------------- deep inverse DFT, LDS-resident -----------------------------
__global__ __launch_bounds__(256) void k_invdeep2(
    const bfu* __restrict__ YT, bfu* __restrict__ Ud, bfu* __restrict__ Us,
    const float* __restrict__ TWc, int h, int l)
{
  int b = blockIdx.x, u = blockIdx.y;
  bfu* outp = (u? Us : Ud) + (size_t)b*h*128;
  const bfu* Y = YT + ((size_t)u*16 + b)*128*128;
  __shared__ float s_yr[128*66];
  __shared__ float s_yi[128*66];
  __shared__ float s_twc[33*64];
  __shared__ float s_tws[33*64];
  int tid = threadIdx.x;
  #pragma unroll
  for(int it=0; it<8; ++it){
    int slot = it*256 + tid;
    int ch = slot >> 4, kq = slot & 15;
    union{uint4 u4; bfu x[8];} U;
    U.u4 = *reinterpret_cast<const uint4*>(&Y[(size_t)ch*128 + kq*8]);
    if(kq < 8){
      #pragma unroll
      for(int j=0;j<8;++j) s_yr[ch*66 + kq*8 + j] = bs2f(U.x[j]);
    } else {
      #pragma unroll
      for(int j=0;j<8;++j) s_yi[ch*66 + (kq-8)*8 + j] = bs2f(U.x[j]);
    }
  }
  int lh = l*h;
  const float* TWs = TWc + (size_t)lh;
  for(int e = tid; e < lh; e += 256){ s_twc[e] = TWc[e]; s_tws[e] = TWs[e]; }
  __syncthreads();
  for(int idx = tid; idx < h*128; idx += 256){
    int t = idx >> 7, ch = idx & 127;
    const float* yr = &s_yr[ch*66];
    const float* yi = &s_yi[ch*66];
    float a = 0.f;
    for(int f=0; f<l; ++f)
      a += yr[f]*s_twc[f*h + t] - yi[f]*s_tws[f*h + t];
    outp[idx] = f2bs(a);
  }
}

// ---------------- LayerNorm + exact GELU on (16,1,128) -----------------------
__global__ __launch_bounds__(128) void k_lngelu(
    const bfu* __restrict__ xin, const bfu* __restrict__ CSM, bfu* __restrict__ xout)
{
  int b = blockIdx.x, tid = threadIdx.x;
  float v = bs2f(xin[b*128 + tid]);
  float s1 = v, s2 = v*v;
  #pragma unroll
  for(int o=32; o; o>>=1){ s1 += __shfl_down(s1,o); s2 += __shfl_down(s2,o); }
  __shared__ float red[2][2];
  int w = tid >> 6;
  if((tid & 63) == 0){ red[w][0]=s1; red[w][1]=s2; }
  __syncthreads();
  float m  = (red[0][0]+red[1][0]) * (1.0f/128.0f);
  float ms = (red[0][1]+red[1][1]) * (1.0f/128.0f);
  float var = ms - m*m;
  float xn = (v - m) * rsqrtf(var + 1e-5f) * bs2f(CSM[512+tid]) + bs2f(CSM[640+tid]);
  float g = 0.5f * xn * (1.0f + erff(xn * 0.70710678118654752f));
  xout[b*128 + tid] = f2bs(g);
}

// ---------------- reconstruction step ([t][ch] layout) -----------------------
__global__ __launch_bounds__(256) void k_recon(
    const bfu* __restrict__ xin, const bfu* __restrict__ usp, const bfu* __restrict__ udp,
    const bfu* __restrict__ CSM, void* __restrict__ xout, int h, int logh,
    int is_final, const int* __restrict__ FLAG)
{
  int f32 = is_final ? FLAG[0] : 0;
  __shared__ float Fe[16][8], Fo[16][8];
  int tid = threadIdx.x;
  if(tid < 128){ Fe[tid>>3][tid&7] = bs2f(CSM[256+tid]); Fo[tid>>3][tid&7] = bs2f(CSM[384+tid]); }
  __syncthreads();
  int idx = blockIdx.x*256 + tid;
  if(idx >= 16*h*16) return;
  int c  = idx & 15;
  int bt = idx >> 4;
  int t  = bt & (h-1);
  int b  = bt >> logh;
  size_t base = (((size_t)bt) << 7) + (c<<3);
  union{ uint4 u; bfu x[8]; } X, U, D;
  X.u = *reinterpret_cast<const uint4*>(xin + base);
  U.u = *reinterpret_cast<const uint4*>(usp + base);
  D.u = *reinterpret_cast<const uint4*>(udp + base);
  float y[16];
  #pragma unroll
  for(int j=0;j<8;++j){ y[j] = bs2f(X.x[j]) + bs2f(U.x[j]); y[8+j] = bs2f(D.x[j]); }
  float e8[8] = {0,0,0,0,0,0,0,0}, o8[8] = {0,0,0,0,0,0,0,0};
  #pragma unroll
  for(int j=0;j<16;++j){
    float v = y[j];
    #pragma unroll
    for(int k=0;k<8;++k){ e8[k] += v*Fe[j][k]; o8[k] += v*Fo[j][k]; }
  }
  size_t ob = (((size_t)(b*(h<<1) + (t<<1))) << 7) + (c<<3);
  if(f32){
    float* po = (float*)xout;
    *reinterpret_cast<float4*>(po + ob)       = make_float4(e8[0],e8[1],e8[2],e8[3]);
    *reinterpret_cast<float4*>(po + ob + 4)   = make_float4(e8[4],e8[5],e8[6],e8[7]);
    *reinterpret_cast<float4*>(po + ob + 128) = make_float4(o8[0],o8[1],o8[2],o8[3]);
    *reinterpret_cast<float4*>(po + ob + 132) = make_float4(o8[4],o8[5],o8[6],o8[7]);
  } else {
    union{ uint4 u; bfu x[8]; } Oe, Oo;
    #pragma unroll
    for(int k=0;k<8;++k){ Oe.x[k] = f2bs(e8[k]); Oo.x[k] = f2bs(o8[k]); }
    bfu* po = (bfu*)xout;
    *reinterpret_cast<uint4*>(po + ob)       = Oe.u;
    *reinterpret_cast<uint4*>(po + ob + 128) = Oo.u;
  }
}

// ============================================================================
extern "C" void kernel_launch(void* const* d_in, const int* in_sizes, int n_in,
                              void* d_out, int out_size, void* d_ws, size_t ws_size,
                              hipStream_t stream)
{
  (void)in_sizes; (void)n_in; (void)out_size; (void)ws_size;
  const void* x0 = d_in[0];
  WPtrs wp;
  for(int w=0;w<6;++w) wp.p[w] = d_in[1+w];

  char* ws = (char*)d_ws;
  size_t off = 0;
  auto carve = [&](size_t bytes)->char*{
    char* p = ws + off; off += (bytes + 255) & ~(size_t)255; return p; };

  int* FLAG = (int*)carve(256);
  bfu* CSM  = (bfu*)carve(2048);
  bfu* SA   = (bfu*)carve((size_t)16*4096*128*2);   // sT even levels
  bfu* SB   = (bfu*)carve((size_t)16*2048*128*2);   // sT odd levels
  bfu *Ud[13], *Us[13];
  for(int i=0;i<13;++i) Ud[i] = (bfu*)carve((size_t)16*(4096>>i)*128*2);
  for(int i=0;i<13;++i) Us[i] = (bfu*)carve((size_t)16*(4096>>i)*128*2);
  bfu*   Dscr = (bfu*)carve((size_t)16*4096*128*2);       // 16 MiB dT scratch
  float* FTP  = (float*)carve((size_t)16*2*16*128*128*4); // 32 MiB partials (np<=16)
  bfu*   YT   = (bfu*)carve((size_t)2*16*128*128*2);      // 1 MiB
  bfu*   WT   = (bfu*)carve((size_t)6*64*128*128*2);      // W2[w][f][o][i]
  bfu*   XA   = (bfu*)carve((size_t)64*32*512*2);         // 2 MiB A-matrices
  bfu*   TWF  = (bfu*)carve((size_t)1032192*2);
  bfu*   TWI  = (bfu*)carve((size_t)1032192*2);
  bfu*   XPA  = Dscr;              // recon ping-pong (reuse, post-spectral)
  bfu*   XPB  = (bfu*)FTP;

  // level params
  int hv[13], lv2[13];
  const int offF[6] = {0,524288,786432,917504,983040,1015808};
  for(int i=0;i<13;++i){
    int h = 4096 >> i;
    int l = (h/2+1) < 64 ? (h/2+1) : 64;
    hv[i]=h; lv2[i]=l;
  }
  // deep fp32 twiddles (levels 6..12)
  LevelTab lt;
  int acc = 0;
  for(int j=0;j<7;++j){
    int i = 6+j;
    lt.twoff[j]=acc; lt.ll[j]=lv2[i]; lt.logh[j]=12-i;
    acc += 2*lv2[i]*hv[i];
  }
  for(int j=7;j<13;++j){ lt.twoff[j]=0; lt.ll[j]=1; lt.logh[j]=0; }
  float* TWD = (float*)carve((size_t)acc*4);

  k_sniff<<<dim3(1),256,0,stream>>>((const bfu*)x0, FLAG);
  k_cvt_small<<<dim3(1),256,0,stream>>>(d_in[7], d_in[8], d_in[9], d_in[10], d_in[11], d_in[12], CSM, FLAG);
  k_wtrans<<<dim3(128,6),256,0,stream>>>(wp, WT, FLAG);
  k_twgenF<<<dim3(4032,2),256,0,stream>>>(TWF, TWI);
  k_twgen<<<dim3(17,7),256,0,stream>>>(lt, TWD);

  bfu* ST[13];
  for(int i=0;i<13;++i) ST[i] = (i&1) ? SB : SA;

  // levels 0..5: MFMA path
  for(int i=0;i<6;++i){
    int h = hv[i];
    int np = (h/64 < 8) ? (h/64) : 8;
    int Kpart = h/np;
    if(i==0){
      k_decomp0<<<dim3(h/32,16),256,0,stream>>>(x0, Dscr, ST[0], CSM, h, FLAG);
    } else if(h >= 256){
      k_decompT_big<<<dim3(h/256,16,16),256,0,stream>>>(ST[i-1], Dscr, ST[i], CSM, h);
    } else {
      int total = 16*16*(h>>2);
      k_decompT<<<dim3((total+255)/256),256,0,stream>>>(ST[i-1], Dscr, ST[i], CSM, h, total);
    }
    k_fwdft_mfma<<<dim3(np,16,4),256,0,stream>>>(Dscr, ST[i], TWF + offF[i], FTP, h, Kpart);
    k_ftpred<<<dim3(512),256,0,stream>>>(FTP, XA, np, 64);
    k_modemix_mfma<<<dim3(64,8),256,0,stream>>>(XA, WT, YT, h);
    k_invdft_mfma<<<dim3(h/128,16,2),256,0,stream>>>(YT, TWI + offF[i], Ud[i], Us[i], h);
  }
  // levels 6..12: deep path, MFMA mode mixing
  for(int i=6;i<13;++i){
    int h = hv[i], l = lv2[i], logh = 12-i;
    int total = (h>=4) ? 16*16*(h>>2) : 256;
    k_decompT<<<dim3((total+255)/256),256,0,stream>>>(ST[i-1], Dscr, ST[i], CSM, h, total);
    const float* cT = TWD + lt.twoff[i-6];
    k_fwdeep2<<<dim3(16,2),256,0,stream>>>(Dscr, ST[i], FTP, cT, h, l, logh);
    k_ftpred<<<dim3(512),256,0,stream>>>(FTP, XA, 1, l);
    k_modemix_mfma<<<dim3(l,8),256,0,stream>>>(XA, WT, YT, h);
    k_invdeep2<<<dim3(16,2),256,0,stream>>>(YT, Ud[i], Us[i], cT, h, l);
  }
  k_lngelu<<<dim3(16),128,0,stream>>>(ST[12], CSM, XPA);
  bfu* rin = XPA;
  for(int i=12;i>=0;--i){
    int h = hv[i];
    void* rout = (i==0) ? d_out : (void*)((rin==XPA) ? XPB : XPA);
    int tot = 16*h*16;
    k_recon<<<dim3((tot+255)/256),256,0,stream>>>(rin, Us[i], Ud[i], CSM, rout, h, 12-i, (i==0)?1:0, FLAG);
    rin = (bfu*)rout;
  }
}

// Round 7
// 514.699 us; speedup vs baseline: 1.3521x; 1.3521x over previous
//
#include <hip/hip_runtime.h>
#include <math.h>

typedef unsigned short bfu;   // raw bf16 bits
typedef short bf16x8 __attribute__((ext_vector_type(8)));
typedef float f32x4 __attribute__((ext_vector_type(4)));

__device__ __forceinline__ float bs2f(bfu s){
  union{ unsigned int u; float f; } v; v.u = ((unsigned int)s) << 16; return v.f;
}
__device__ __forceinline__ bfu f2bs(float f){
  union{ float ff; unsigned int u; } v; v.ff = f;
  unsigned int u = v.u;
  unsigned int r = (u + 0x7fffu + ((u >> 16) & 1u)) >> 16;   // RNE
  return (bfu)r;
}

struct LevelTab { int twoff[13]; int ll[13]; int logh[13]; };
struct WPtrs { const void* p[6]; };
struct FwTab { int pcum[7]; int h[6]; int np[6]; int twF[6]; long lvl[6]; long ftp[6]; };
struct DpTab { long lvl[7]; long ftp[7]; long yt[7]; int twD[7]; int h[7]; int l[7]; int lgh[7]; };
struct PrTab { int np[13]; int l[13]; long ftp[13]; long xa[13]; };
struct MxTab { int fcum[13]; int h[13]; long xa[13]; long yt[13]; };
struct IvTab { int bxcum[6]; int h[6]; int twF[6]; long yt[6]; long lvl[6]; };

// ---------------- dtype sniff ------------------------------------------------
__global__ __launch_bounds__(256) void k_sniff(const bfu* __restrict__ x, int* __restrict__ flag){
  __shared__ int cnt;
  if(threadIdx.x==0) cnt = 0;
  __syncthreads();
  int c = 0;
  for(int j=threadIdx.x; j<4096; j+=256){
    bfu v = x[2*j];
    int e = (v>>7)&0xFF;
    if(e >= 0xC0) c++;
  }
  atomicAdd(&cnt, c);
  __syncthreads();
  if(threadIdx.x==0) flag[0] = (cnt > 64) ? 1 : 0;
}

// ---------------- small arrays -> bf16 ---------------------------------------
__global__ __launch_bounds__(256) void k_cvt_small(
    const void* lnw, const void* lnb, const void* ecs, const void* ecd,
    const void* rce, const void* rco, bfu* __restrict__ CSM, const int* __restrict__ FLAG){
  int f32 = FLAG[0];
  const void* src[6] = {ecs, ecd, rce, rco, lnw, lnb};
  int tid = threadIdx.x;
  for(int a=0; a<6; ++a)
    for(int j=tid; j<128; j+=256)
      CSM[a*128+j] = f32 ? f2bs(((const float*)src[a])[j]) : ((const bfu*)src[a])[j];
}

// ---------------- weight transpose: W[i][o][f] -> W2[w][f][o][i], bf16 -------
__global__ __launch_bounds__(256) void k_wtrans(WPtrs wp, bfu* __restrict__ W2, const int* __restrict__ FLAG){
  int f32 = FLAG[0];
  int o = blockIdx.x;          // 0..127
  int w = blockIdx.y;          // 0..5
  __shared__ bfu tile[64][130];   // [f][i]
  int tid = threadIdx.x;
  const void* src = wp.p[w];
  if(f32){
    const float* s = (const float*)src;
    #pragma unroll
    for(int it=0; it<8; ++it){
      int e = it*256 + tid;
      int i = e >> 4, fq = e & 15;
      float4 v = *reinterpret_cast<const float4*>(s + ((size_t)i*128 + o)*64 + fq*4);
      tile[fq*4+0][i] = f2bs(v.x);
      tile[fq*4+1][i] = f2bs(v.y);
      tile[fq*4+2][i] = f2bs(v.z);
      tile[fq*4+3][i] = f2bs(v.w);
    }
  } else {
    const bfu* s = (const bfu*)src;
    #pragma unroll
    for(int it=0; it<4; ++it){
      int e = it*256 + tid;
      int i = e >> 3, fq = e & 7;
      union{uint4 u; bfu x[8];} U;
      U.u = *reinterpret_cast<const uint4*>(s + ((size_t)i*128 + o)*64 + fq*8);
      #pragma unroll
      for(int j=0;j<8;++j) tile[fq*8+j][i] = U.x[j];
    }
  }
  __syncthreads();
  bfu* dst = W2 + (size_t)w*64*128*128 + (size_t)o*128;
  #pragma unroll
  for(int it=0; it<8; ++it){
    int e = it*256 + tid;
    int f = e >> 5, iq = e & 31;
    union{uint2 u; bfu x[4];} P;
    #pragma unroll
    for(int j=0;j<4;++j) P.x[j] = tile[f][iq*4+j];
    *reinterpret_cast<uint2*>(dst + (size_t)f*128*128 + iq*4) = P.u;
  }
}

// ---------------- bf16 twiddle matrices for MFMA levels 0..5 -----------------
__global__ __launch_bounds__(256) void k_twgenF(bfu* __restrict__ TWF, bfu* __restrict__ TWI){
  int e = blockIdx.x*256 + threadIdx.x;      // 0..1032191
  int kind = blockIdx.y;
  const int offs[7] = {0,524288,786432,917504,983040,1015808,1032192};
  int le = 5;
  #pragma unroll
  for(int i=0;i<6;++i){ if(e < offs[i+1]){ le = i; break; } }
  int rem = e - offs[le];
  int logh = 12 - le;
  int h = 1 << logh;
  int f, t, neg;
  if(kind==0){ int r = rem >> logh; t = rem & (h-1); f = (r<64)?r:(r-64); neg = (r>=64); }
  else       { t = rem >> 7; int f2 = rem & 127;     f = (f2<64)?f2:(f2-64); neg = (f2>=64); }
  int m = (f*t) & (h-1);
  float th = 6.283185307179586f * ((float)m / (float)h);
  float s, c; sincosf(th, &s, &c);
  float val = neg ? -s : c;
  if(kind==0) TWF[e] = f2bs(val); else TWI[e] = f2bs(val);
}

// ---------------- fp32 twiddles for deep levels ------------------------------
__global__ __launch_bounds__(256) void k_twgen(LevelTab lt, float* __restrict__ tw){
  int lev = blockIdx.y;
  int logh = lt.logh[lev];
  int h = 1 << logh;
  int l = lt.ll[lev];
  int tot = l*h;
  int idx = blockIdx.x*256 + threadIdx.x;
  if(idx >= tot) return;
  int t = idx & (h-1);
  int f = idx >> logh;
  int m = (f*t) & (h-1);
  float th = 6.283185307179586f * ((float)m / (float)h);
  float s, c; sincosf(th, &s, &c);
  tw[lt.twoff[lev] + idx] = c;
  tw[lt.twoff[lev] + tot + idx] = s;
}

// ---------------- level-0 decompose v3 ---------------------------------------
__global__ __launch_bounds__(256) void k_decomp0(
    const void* __restrict__ xin, bfu* __restrict__ dT, bfu* __restrict__ sT,
    const bfu* __restrict__ CSM, int h, const int* __restrict__ FLAG)
{
  int f32 = FLAG[0];
  __shared__ float ls[64][132];
  __shared__ bfu sdo[128][36];
  __shared__ bfu sso[128][36];
  __shared__ float Fd[16][8], Fs[16][8];
  int tid = threadIdx.x;
  if(tid < 128){ Fs[tid>>3][tid&7] = bs2f(CSM[tid]); Fd[tid>>3][tid&7] = bs2f(CSM[128+tid]); }
  int b = blockIdx.y;
  int t0in = blockIdx.x * 64;
  if(f32){
    const float* src = (const float*)xin + ((size_t)b*2*h + t0in)*128;
    #pragma unroll
    for(int it=0; it<8; ++it){
      int e = it*256 + tid;
      int row = e>>5, cq = e&31;
      float4 v = *reinterpret_cast<const float4*>(src + (size_t)row*128 + cq*4);
      ls[row][cq*4+0]=v.x; ls[row][cq*4+1]=v.y; ls[row][cq*4+2]=v.z; ls[row][cq*4+3]=v.w;
    }
  } else {
    const bfu* src = (const bfu*)xin + ((size_t)b*2*h + t0in)*128;
    #pragma unroll
    for(int it=0; it<4; ++it){
      int e = it*256 + tid;
      int row = e>>4, cq = e&15;
      union{uint4 u; bfu x[8];} U;
      U.u = *reinterpret_cast<const uint4*>(src + (size_t)row*128 + cq*8);
      #pragma unroll
      for(int j=0;j<8;++j) ls[row][cq*8+j] = bs2f(U.x[j]);
    }
  }
  __syncthreads();
  int g = tid>>7, ch = tid&127;
  int c = ch>>3, kp = ch&7;
  float fdE[8], fdO[8], fsE[8], fsO[8];
  #pragma unroll
  for(int j=0;j<8;++j){ fdE[j]=Fd[j][kp]; fdO[j]=Fd[8+j][kp]; fsE[j]=Fs[j][kp]; fsO[j]=Fs[8+j][kp]; }
  union{ uint2 u; bfu x[4]; } Dq, Sq;
  #pragma unroll
  for(int tl=0; tl<16; ++tl){
    int rl = 2*(g*16+tl);
    const float* ev = &ls[rl][c*8];
    const float* od = &ls[rl+1][c*8];
    float d=0.f, s=0.f;
    #pragma unroll
    for(int j=0;j<8;++j){
      d += ev[j]*fdE[j] + od[j]*fdO[j];
      s += ev[j]*fsE[j] + od[j]*fsO[j];
    }
    Dq.x[tl&3] = f2bs(d); Sq.x[tl&3] = f2bs(s);
    if((tl&3)==3){
      int tb = g*16 + (tl & ~3);
      *reinterpret_cast<uint2*>(&sdo[ch][tb]) = Dq.u;
      *reinterpret_cast<uint2*>(&sso[ch][tb]) = Sq.u;
    }
  }
  __syncthreads();
  size_t obase = (size_t)b*128*h + (t0in>>1);
  #pragma unroll
  for(int it=0; it<4; ++it){
    int e = it*256 + tid;
    int r = e >> 3, kq = e & 7;
    union{uint2 u; bfu x[4];} P;
    #pragma unroll
    for(int j=0;j<4;++j) P.x[j] = sdo[r][kq*4+j];
    *reinterpret_cast<uint2*>(dT + obase + (size_t)r*h + kq*4) = P.u;
  }
  #pragma unroll
  for(int it=0; it<4; ++it){
    int e = it*256 + tid;
    int r = e >> 3, kq = e & 7;
    union{uint2 u; bfu x[4];} P;
    #pragma unroll
    for(int j=0;j<4;++j) P.x[j] = sso[r][kq*4+j];
    *reinterpret_cast<uint2*>(sT + obase + (size_t)r*h + kq*4) = P.u;
  }
}

// ---------------- transposed decompose, big levels (h >= 256) ----------------
__global__ __launch_bounds__(256) void k_decompT_big(
    const bfu* __restrict__ inT, bfu* __restrict__ dT, bfu* __restrict__ sT,
    const bfu* __restrict__ CSM, int h)
{
  __shared__ float Fd[16][8], Fs[16][8];
  int tid = threadIdx.x;
  if(tid < 128){ Fs[tid>>3][tid&7] = bs2f(CSM[tid]); Fd[tid>>3][tid&7] = bs2f(CSM[128+tid]); }
  __syncthreads();
  int tt0 = blockIdx.x * 256;
  int b = blockIdx.y, c = blockIdx.z;
  int kp = tid >> 5, tq = tid & 31;
  float fdE[8], fdO[8], fsE[8], fsO[8];
  #pragma unroll
  for(int k=0;k<8;++k){ fdE[k]=Fd[k][kp]; fdO[k]=Fd[8+k][kp]; fsE[k]=Fs[k][kp]; fsO[k]=Fs[8+k][kp]; }
  const bfu* base = inT + ((size_t)b*128 + c*8)*(size_t)(2*h) + (size_t)2*tt0 + tq*16;
  union{uint4 u[2]; bfu x[16];} E[8];
  #pragma unroll
  for(int k=0;k<8;++k){
    E[k].u[0] = *reinterpret_cast<const uint4*>(base + (size_t)k*(2*h));
    E[k].u[1] = *reinterpret_cast<const uint4*>(base + (size_t)k*(2*h) + 8);
  }
  union{uint4 u; bfu x[8];} Od, Os;
  #pragma unroll
  for(int to=0; to<8; ++to){
    float d=0.f, s=0.f;
    #pragma unroll
    for(int k=0;k<8;++k){
      float ev = bs2f(E[k].x[2*to]), od = bs2f(E[k].x[2*to+1]);
      d += ev*fdE[k] + od*fdO[k];
      s += ev*fsE[k] + od*fsO[k];
    }
    Od.x[to] = f2bs(d); Os.x[to] = f2bs(s);
  }
  size_t ob = ((size_t)b*128 + c*8 + kp)*h + tt0 + tq*8;
  *reinterpret_cast<uint4*>(dT + ob) = Od.u;
  *reinterpret_cast<uint4*>(sT + ob) = Os.u;
}

// ---------------- transposed decompose (small levels) ------------------------
__global__ __launch_bounds__(256) void k_decompT(
    const bfu* __restrict__ inT, bfu* __restrict__ dT, bfu* __restrict__ sT,
    const bfu* __restrict__ CSM, int h, int total)
{
  __shared__ float Fd[16][8], Fs[16][8];
  int tid = threadIdx.x;
  if(tid < 128){ Fs[tid>>3][tid&7] = bs2f(CSM[tid]); Fd[tid>>3][tid&7] = bs2f(CSM[128+tid]); }
  __syncthreads();
  int idx = blockIdx.x*256 + tid;
  if(idx >= total) return;
  if(h >= 4){
    int nto = h>>2;
    int to = idx & (nto-1);
    int bc = idx / nto;
    int c = bc & 15, b = bc >> 4;
    const bfu* base = inT + ((size_t)b*128 + c*8)*(size_t)(2*h) + to*8;
    float d8[4][8] = {}, s8[4][8] = {};
    #pragma unroll
    for(int k=0;k<8;++k){
      union{uint4 u; bfu x[8];} U;
      U.u = *reinterpret_cast<const uint4*>(base + (size_t)k*(2*h));
      const float* fdE = Fd[k]; const float* fdO = Fd[8+k];
      const float* fsE = Fs[k]; const float* fsO = Fs[8+k];
      #pragma unroll
      for(int tl=0; tl<4; ++tl){
        float ev = bs2f(U.x[2*tl]), od = bs2f(U.x[2*tl+1]);
        #pragma unroll
        for(int kp=0;kp<8;++kp){
          d8[tl][kp] += ev*fdE[kp] + od*fdO[kp];
          s8[tl][kp] += ev*fsE[kp] + od*fsO[kp];
        }
      }
    }
    #pragma unroll
    for(int kp=0;kp<8;++kp){
      union{uint2 u; bfu x[4];} Od, Os;
      #pragma unroll
      for(int tl=0;tl<4;++tl){ Od.x[tl]=f2bs(d8[tl][kp]); Os.x[tl]=f2bs(s8[tl][kp]); }
      size_t ob = ((size_t)b*128 + c*8 + kp)*h + to*4;
      *reinterpret_cast<uint2*>(dT + ob) = Od.u;
      *reinterpret_cast<uint2*>(sT + ob) = Os.u;
    }
  } else {
    int c = idx & 15, b = idx >> 4;
    const bfu* base = inT + ((size_t)b*128 + c*8)*(size_t)(2*h);
    for(int tl=0; tl<h; ++tl){
      float d8[8]={}, s8[8]={};
      for(int k=0;k<8;++k){
        float ev = bs2f(base[(size_t)k*2*h + 2*tl]);
        float od = bs2f(base[(size_t)k*2*h + 2*tl+1]);
        #pragma unroll
        for(int kp=0;kp<8;++kp){
          d8[kp] += ev*Fd[k][kp] + od*Fd[8+k][kp];
          s8[kp] += ev*Fs[k][kp] + od*Fs[8+k][kp];
        }
      }
      for(int kp=0;kp<8;++kp){
        size_t ob = ((size_t)b*128 + c*8 + kp)*h + tl;
        dT[ob] = f2bs(d8[kp]); sT[ob] = f2bs(s8[kp]);
      }
    }
  }
}

// ---------------- MFMA forward DFT, batched levels 0..5 ----------------------
// grid (pcum[6], 16 b, 4): z = sig*2 + rh.
__global__ __launch_bounds__(256) void k_fwdft_all(
    const bfu* __restrict__ DTall, const bfu* __restrict__ STall,
    const bfu* __restrict__ TWF, float* __restrict__ FTPa, FwTab ft)
{
  int gp = blockIdx.x, b = blockIdx.y;
  int sig = blockIdx.z >> 1, rh = blockIdx.z & 1;
  int lev = 0;
  for(int i=5;i>0;--i){ if(gp >= ft.pcum[i]){ lev = i; break; } }
  int p = gp - ft.pcum[lev];
  int h = ft.h[lev];
  int Kpart = h / ft.np[lev];
  const bfu* SIG = (sig ? STall : DTall) + ft.lvl[lev] + (size_t)b*128*h;
  const bfu* TWr = TWF + ft.twF[lev] + (size_t)(rh*64)*h;
  __shared__ bfu lsA[64*72];
  __shared__ bfu lsB[128*72];
  int tid = threadIdx.x;
  int wave = tid>>6, lane = tid&63;
  int mh = (wave>>1)*32, nh = (wave&1)*64;
  int ml = lane&15, q = lane>>4;
  f32x4 acc[2][4];
  #pragma unroll
  for(int i=0;i<2;++i){
    #pragma unroll
    for(int j=0;j<4;++j) acc[i][j] = (f32x4)0.f;
  }
  int k0base = p*Kpart;
  for(int kc=0; kc<Kpart; kc+=64){
    int k0 = k0base + kc;
    #pragma unroll
    for(int it=0; it<2; ++it){
      int slot = it*256 + tid;
      int row = slot>>3, kq = slot&7;
      *reinterpret_cast<uint4*>(&lsA[row*72 + kq*8]) =
        *reinterpret_cast<const uint4*>(&TWr[(size_t)row*h + k0 + kq*8]);
    }
    #pragma unroll
    for(int it=0; it<4; ++it){
      int slot = it*256 + tid;
      int row = slot>>3, kq = slot&7;
      *reinterpret_cast<uint4*>(&lsB[row*72 + kq*8]) =
        *reinterpret_cast<const uint4*>(&SIG[(size_t)row*h + k0 + kq*8]);
    }
    __syncthreads();
    #pragma unroll
    for(int kk=0; kk<64; kk+=32){
      bf16x8 af[2], bfr[4];
      #pragma unroll
      for(int mi=0;mi<2;++mi)
        af[mi] = *reinterpret_cast<const bf16x8*>(&lsA[(mh+mi*16+ml)*72 + kk + q*8]);
      #pragma unroll
      for(int ni=0;ni<4;++ni)
        bfr[ni] = *reinterpret_cast<const bf16x8*>(&lsB[(nh+ni*16+ml)*72 + kk + q*8]);
      #pragma unroll
      for(int mi=0;mi<2;++mi){
        #pragma unroll
        for(int ni=0;ni<4;++ni)
          acc[mi][ni] = __builtin_amdgcn_mfma_f32_16x16x32_bf16(af[mi], bfr[ni], acc[mi][ni], 0,0,0);
      }
    }
    __syncthreads();
  }
  float* dst = FTPa + ft.ftp[lev] + (((size_t)p*2 + sig)*16 + b)*16384;
  #pragma unroll
  for(int mi=0;mi<2;++mi){
    #pragma unroll
    for(int ni=0;ni<4;++ni){
      int row = rh*64 + mh + mi*16 + q*4;
      int col = nh + ni*16 + ml;
      #pragma unroll
      for(int r=0;r<4;++r)
        dst[(size_t)(row+r)*128 + col] = acc[mi][ni][r];
    }
  }
}

// ---------------- deep forward DFT, batched levels 6..12 ---------------------
// grid (16 b, 2 sig, 7 j)
__global__ __launch_bounds__(256) void k_fwdeep_all(
    const bfu* __restrict__ DTall, const bfu* __restrict__ STall,
    float* __restrict__ FTPa, const float* __restrict__ TWD, DpTab dp)
{
  int b = blockIdx.x, sig = blockIdx.y, j = blockIdx.z;
  int h = dp.h[j], l = dp.l[j], logh = dp.lgh[j];
  const bfu* src = (sig? STall : DTall) + dp.lvl[j] + (size_t)b*128*h;
  float* dst = FTPa + dp.ftp[j] + ((size_t)sig*16 + b)*16384;
  const float* TWc = TWD + dp.twD[j];
  __shared__ float s_sig[128*65];
  __shared__ float s_twc[33*64];
  __shared__ float s_tws[33*64];
  int tid = threadIdx.x;
  int hp = h + 1;
  for(int e = tid; e < 128*h; e += 256){
    int ch = e >> logh, t = e & (h-1);
    s_sig[ch*hp + t] = bs2f(src[e]);
  }
  int lh = l*h;
  const float* TWs = TWc + (size_t)lh;
  for(int e = tid; e < lh; e += 256){ s_twc[e] = TWc[e]; s_tws[e] = TWs[e]; }
  __syncthreads();
  for(int idx = tid; idx < l*128; idx += 256){
    int f = idx >> 7, ch = idx & 127;
    const float* sp = &s_sig[ch*hp];
    const float* cp = &s_twc[f*h];
    const float* zp = &s_tws[f*h];
    float re = 0.f, im = 0.f;
    for(int t=0; t<h; ++t){ float v = sp[t]; re += v*cp[t]; im -= v*zp[t]; }
    dst[(size_t)f*128 + ch] = re;
    dst[(size_t)(64+f)*128 + ch] = im;
  }
}

// ---------------- FTP reduce + A-matrix build, batched all levels ------------
// grid (512, 13)
__global__ __launch_bounds__(256) void k_ftpred_all(
    const float* __restrict__ FTPa, bfu* __restrict__ XAa, PrTab pt)
{
  int lev = blockIdx.y;
  int e = blockIdx.x*256 + threadIdx.x;     // 0..131071
  const size_t PS = (size_t)2*16*128*128;
  int ch4 = e & 31;
  int row = (e>>5) & 127;
  int b   = (e>>12) & 15;
  int sig = e>>16;
  int f = row & 63, im = row >> 6;
  if(f >= pt.l[lev]) return;
  const float* F = FTPa + pt.ftp[lev];
  int np = pt.np[lev];
  size_t src = (((size_t)sig*16 + b)*128 + row)*128 + (size_t)ch4*4;
  f32x4 v = *reinterpret_cast<const f32x4*>(&F[src]);
  for(int p=1;p<np;++p)
    v += *reinterpret_cast<const f32x4*>(&F[src + (size_t)p*PS]);
  int ch = ch4*4;
  union{ uint2 u; bfu x[4]; } P1, P3;
  #pragma unroll
  for(int j=0;j<4;++j){
    float vj = v[j];
    P1.x[j] = f2bs(im ? -vj : vj);
    P3.x[j] = f2bs(vj);
  }
  bfu* XA = XAa + pt.xa[lev];
  size_t base = (size_t)f*32*512;
  *reinterpret_cast<uint2*>(&XA[base + (size_t)b*512 + sig*256 + im*128 + ch]) = P1.u;
  *reinterpret_cast<uint2*>(&XA[base + (size_t)(16+b)*512 + sig*256 + (1-im)*128 + ch]) = P3.u;
}

// ---------------- MFMA mode mixing, batched all levels -----------------------
// grid (fcum_total, 8 og)
__global__ __launch_bounds__(256) void k_modemix_all(
    const bfu* __restrict__ XAa, const bfu* __restrict__ W2,
    bfu* __restrict__ YTa, MxTab mt)
{
  int x = blockIdx.x;
  int lev = 0;
  for(int i=12;i>0;--i){ if(x >= mt.fcum[i]){ lev = i; break; } }
  int f = x - mt.fcum[lev];
  int h = mt.h[lev];
  int obase = blockIdx.y * 16;
  int tid = threadIdx.x;
  int wid = tid>>6, lane = tid&63;
  int m = wid & 1, part = wid >> 1;
  int ml = lane & 15, q = lane >> 4;
  const size_t WSZ = (size_t)64*128*128;
  const bfu* Ab = XAa + mt.xa[lev] + ((size_t)f*32 + m*16 + ml)*512 + q*8;
  const bfu* Wb = W2 + ((size_t)f*128 + obase + ml)*128 + q*8;
  f32x4 acc = (f32x4)0.f;
  if(part == 0){
    #pragma unroll
    for(int ks=0; ks<16; ++ks){
      bf16x8 A = *reinterpret_cast<const bf16x8*>(Ab + ks*32);
      bf16x8 B = *reinterpret_cast<const bf16x8*>(Wb + (size_t)(ks>>2)*WSZ + (ks&3)*32);
      acc = __builtin_amdgcn_mfma_f32_16x16x32_bf16(A, B, acc, 0,0,0);
    }
  } else {
    #pragma unroll
    for(int ks=0; ks<8; ++ks){
      bf16x8 A = *reinterpret_cast<const bf16x8*>(Ab + ks*32);
      bf16x8 B = *reinterpret_cast<const bf16x8*>(Wb + (size_t)(4 + (ks>>2))*WSZ + (ks&3)*32);
      acc = __builtin_amdgcn_mfma_f32_16x16x32_bf16(A, B, acc, 0,0,0);
    }
  }
  bool edge = (f==0) || (2*f == h);
  float sc = edge ? 1.0f/(float)h : 2.0f/(float)h;
  int fo = m ? (64+f) : f;
  int o = obase + ml;
  bfu* dst = YTa + mt.yt[lev] + (part ? (size_t)16*128*128 : 0);
  #pragma unroll
  for(int r=0;r<4;++r){
    int b = q*4 + r;
    float val = acc[r]*sc;
    if(m && edge) val = 0.f;
    dst[((size_t)b*128 + o)*128 + fo] = f2bs(val);
  }
}

// ---------------- MFMA inverse DFT, batched levels 0..5 ----------------------
// grid (bxcum_total=63, 16 b, 2 u)
__global__ __launch_bounds__(256) void k_invdft_all(
    const bfu* __restrict__ YTa, const bfu* __restrict__ TWI,
    bfu* __restrict__ UdAll, bfu* __restrict__ UsAll, IvTab iv)
{
  int x = blockIdx.x, b = blockIdx.y, u = blockIdx.z;
  int lev = 0;
  for(int i=5;i>0;--i){ if(x >= iv.bxcum[i]){ lev = i; break; } }
  int bx = x - iv.bxcum[lev];
  int h = iv.h[lev];
  bfu* outp = (u ? UsAll : UdAll) + iv.lvl[lev];
  const bfu* Y = YTa + iv.yt[lev] + ((size_t)u*16 + b)*16384;
  const bfu* TWIl = TWI + iv.twF[lev];
  int t0 = bx*128;
  __shared__ bfu lsA[128*136];
  __shared__ bfu lsB[128*136];
  int tid = threadIdx.x;
  #pragma unroll
  for(int it=0; it<8; ++it){
    int slot = it*256 + tid;
    int row = slot>>4, kq = slot&15;
    *reinterpret_cast<uint4*>(&lsA[row*136 + kq*8]) =
      *reinterpret_cast<const uint4*>(&TWIl[(size_t)(t0+row)*128 + kq*8]);
    *reinterpret_cast<uint4*>(&lsB[row*136 + kq*8]) =
      *reinterpret_cast<const uint4*>(&Y[(size_t)row*128 + kq*8]);
  }
  __syncthreads();
  int wave = tid>>6, lane = tid&63;
  int mh = (wave>>1)*64, nh = (wave&1)*64;
  int ml = lane&15, q = lane>>4;
  f32x4 acc[4][4];
  #pragma unroll
  for(int i=0;i<4;++i){
    #pragma unroll
    for(int j=0;j<4;++j) acc[i][j] = (f32x4)0.f;
  }
  #pragma unroll
  for(int kk=0; kk<128; kk+=32){
    bf16x8 af[4], bfr[4];
    #pragma unroll
    for(int mi=0;mi<4;++mi)
      af[mi] = *reinterpret_cast<const bf16x8*>(&lsA[(mh+mi*16+ml)*136 + kk + q*8]);
    #pragma unroll
    for(int ni=0;ni<4;++ni)
      bfr[ni] = *reinterpret_cast<const bf16x8*>(&lsB[(nh+ni*16+ml)*136 + kk + q*8]);
    #pragma unroll
    for(int mi=0;mi<4;++mi){
      #pragma unroll
      for(int ni=0;ni<4;++ni)
        acc[mi][ni] = __builtin_amdgcn_mfma_f32_16x16x32_bf16(af[mi], bfr[ni], acc[mi][ni], 0,0,0);
    }
  }
  #pragma unroll
  for(int mi=0;mi<4;++mi){
    #pragma unroll
    for(int ni=0;ni<4;++ni){
      int row = mh + mi*16 + q*4;
      int col = nh + ni*16 + ml;
      #pragma unroll
      for(int r=0;r<4;++r)
        outp[((size_t)b*h + t0+row+r)*128 + col] = f2bs(acc[mi][ni][r]);
    }
  }
}

// ---------------- deep inverse DFT, batched levels 6..12 ---------------------
// grid (16 b, 2 u, 7 j)
__global__ __launch_bounds__(256) void k_invdeep_all(
    const bfu* __restrict__ YTa, bfu* __restrict__ UdAll, bfu* __restrict__ UsAll,
    const float* __restrict__ TWD, DpTab dp)
{
  int b = blockIdx.x, u = blockIdx.y, j = blockIdx.z;
  int h = dp.h[j], l = dp.l[j];
  bfu* outp = (u? UsAll : UdAll) + dp.lvl[j] + (size_t)b*h*128;
  const bfu* Y = YTa + dp.yt[j] + ((size_t)u*16 + b)*16384;
  const float* TWc = TWD + dp.twD[j];
  __shared__ float s_yr[128*66];
  __shared__ float s_yi[128*66];
  __shared__ float s_twc[33*64];
  __shared__ float s_tws[33*64];
  int tid = threadIdx.x;
  #pragma unroll
  for(int it=0; it<8; ++it){
    int slot = it*256 + tid;
    int ch = slot >> 4, kq = slot & 15;
    union{uint4 u4; bfu x[8];} U;
    U.u4 = *reinterpret_cast<const uint4*>(&Y[(size_t)ch*128 + kq*8]);
    if(kq < 8){
      #pragma unroll
      for(int jj=0;jj<8;++jj) s_yr[ch*66 + kq*8 + jj] = bs2f(U.x[jj]);
    } else {
      #pragma unroll
      for(int jj=0;jj<8;++jj) s_yi[ch*66 + (kq-8)*8 + jj] = bs2f(U.x[jj]);
    }
  }
  int lh = l*h;
  const float* TWs = TWc + (size_t)lh;
  for(int e = tid; e < lh; e += 256){ s_twc[e] = TWc[e]; s_tws[e] = TWs[e]; }
  __syncthreads();
  for(int idx = tid; idx < h*128; idx += 256){
    int t = idx >> 7, ch = idx & 127;
    const float* yr = &s_yr[ch*66];
    const float* yi = &s_yi[ch*66];
    float a = 0.f;
    for(int f=0; f<l; ++f)
      a += yr[f]*s_twc[f*h + t] - yi[f]*s_tws[f*h + t];
    outp[idx] = f2bs(a);
  }
}

// ---------------- LayerNorm + exact GELU on (16,1,128) -----------------------
__global__ __launch_bounds__(128) void k_lngelu(
    const bfu* __restrict__ xin, const bfu* __restrict__ CSM, bfu* __restrict__ xout)
{
  int b = blockIdx.x, tid = threadIdx.x;
  float v = bs2f(xin[b*128 + tid]);
  float s1 = v, s2 = v*v;
  #pragma unroll
  for(int o=32; o; o>>=1){ s1 += __shfl_down(s1,o); s2 += __shfl_down(s2,o); }
  __shared__ float red[2][2];
  int w = tid >> 6;
  if((tid & 63) == 0){ red[w][0]=s1; red[w][1]=s2; }
  __syncthreads();
  float m  = (red[0][0]+red[1][0]) * (1.0f/128.0f);
  float ms = (red[0][1]+red[1][1]) * (1.0f/128.0f);
  float var = ms - m*m;
  float xn = (v - m) * rsqrtf(var + 1e-5f) * bs2f(CSM[512+tid]) + bs2f(CSM[640+tid]);
  float g = 0.5f * xn * (1.0f + erff(xn * 0.70710678118654752f));
  xout[b*128 + tid] = f2bs(g);
}

// ---------------- reconstruction step ([t][ch] layout) -----------------------
__global__ __launch_bounds__(256) void k_recon(
    const bfu* __restrict__ xin, const bfu* __restrict__ usp, const bfu* __restrict__ udp,
    const bfu* __restrict__ CSM, void* __restrict__ xout, int h, int logh,
    int is_final, const int* __restrict__ FLAG)
{
  int f32 = is_final ? FLAG[0] : 0;
  __shared__ float Fe[16][8], Fo[16][8];
  int tid = threadIdx.x;
  if(tid < 128){ Fe[tid>>3][tid&7] = bs2f(CSM[256+tid]); Fo[tid>>3][tid&7] = bs2f(CSM[384+tid]); }
  __syncthreads();
  int idx = blockIdx.x*256 + tid;
  if(idx >= 16*h*16) return;
  int c  = idx & 15;
  int bt = idx >> 4;
  int t  = bt & (h-1);
  int b  = bt >> logh;
  size_t base = (((size_t)bt) << 7) + (c<<3);
  union{ uint4 u; bfu x[8]; } X, U, D;
  X.u = *reinterpret_cast<const uint4*>(xin + base);
  U.u = *reinterpret_cast<const uint4*>(usp + base);
  D.u = *reinterpret_cast<const uint4*>(udp + base);
  float y[16];
  #pragma unroll
  for(int j=0;j<8;++j){ y[j] = bs2f(X.x[j]) + bs2f(U.x[j]); y[8+j] = bs2f(D.x[j]); }
  float e8[8] = {0,0,0,0,0,0,0,0}, o8[8] = {0,0,0,0,0,0,0,0};
  #pragma unroll
  for(int j=0;j<16;++j){
    float v = y[j];
    #pragma unroll
    for(int k=0;k<8;++k){ e8[k] += v*Fe[j][k]; o8[k] += v*Fo[j][k]; }
  }
  size_t ob = (((size_t)(b*(h<<1) + (t<<1))) << 7) + (c<<3);
  if(f32){
    float* po = (float*)xout;
    *reinterpret_cast<float4*>(po + ob)       = make_float4(e8[0],e8[1],e8[2],e8[3]);
    *reinterpret_cast<float4*>(po + ob + 4)   = make_float4(e8[4],e8[5],e8[6],e8[7]);
    *reinterpret_cast<float4*>(po + ob + 128) = make_float4(o8[0],o8[1],o8[2],o8[3]);
    *reinterpret_cast<float4*>(po + ob + 132) = make_float4(o8[4],o8[5],o8[6],o8[7]);
  } else {
    union{ uint4 u; bfu x[8]; } Oe, Oo;
    #pragma unroll
    for(int k=0;k<8;++k){ Oe.x[k] = f2bs(e8[k]); Oo.x[k] = f2bs(o8[k]); }
    bfu* po = (bfu*)xout;
    *reinterpret_cast<uint4*>(po + ob)       = Oe.u;
    *reinterpret_cast<uint4*>(po + ob + 128) = Oo.u;
  }
}

// ============================================================================
extern "C" void kernel_launch(void* const* d_in, const int* in_sizes, int n_in,
                              void* d_out, int out_size, void* d_ws, size_t ws_size,
                              hipStream_t stream)
{
  (void)in_sizes; (void)n_in; (void)out_size; (void)ws_size;
  const void* x0 = d_in[0];
  WPtrs wp;
  for(int w=0;w<6;++w) wp.p[w] = d_in[1+w];

  char* ws = (char*)d_ws;
  size_t off = 0;
  auto carve = [&](size_t bytes)->char*{
    char* p = ws + off; off += (bytes + 255) & ~(size_t)255; return p; };

  // level params
  int hv[13], lv[13], npv[13];
  const int offF[6] = {0,524288,786432,917504,983040,1015808};
  for(int i=0;i<13;++i){
    hv[i] = 4096 >> i;
    int l = hv[i]/2 + 1;
    lv[i] = (l < 64) ? l : 64;
    npv[i] = (i < 6) ? ((hv[i]/1024 > 0) ? hv[i]/1024 : 1) : 1;   // 4,2,1,1,1,1,1...
  }
  long lvl[13]; long aTot = 0;
  for(int i=0;i<13;++i){ lvl[i] = aTot; aTot += (long)16*128*hv[i]; }
  long ftpo[13]; long fsl = 0;
  for(int i=0;i<13;++i){ ftpo[i] = fsl*524288L; fsl += npv[i]; }
  long xao[13]; long xsl = 0;
  for(int i=0;i<13;++i){ xao[i] = xsl; xsl += (long)lv[i]*16384; }
  long yto[13];
  for(int i=0;i<13;++i) yto[i] = (long)i*524288;

  int* FLAG = (int*)carve(256);
  bfu* CSM  = (bfu*)carve(2048);
  bfu* STall = (bfu*)carve((size_t)aTot*2);
  bfu* DTall = (bfu*)carve((size_t)aTot*2);
  bfu* UdAll = (bfu*)carve((size_t)aTot*2);
  bfu* UsAll = (bfu*)carve((size_t)aTot*2);
  bfu* WT   = (bfu*)carve((size_t)6*64*128*128*2);
  bfu* XAa  = (bfu*)carve((size_t)xsl*2);
  bfu* YTa  = (bfu*)carve((size_t)13*524288*2);
  bfu* TWF  = (bfu*)carve((size_t)1032192*2);
  bfu* TWI  = (bfu*)carve((size_t)1032192*2);
  float* FTPa = (float*)carve((size_t)fsl*524288*4);

  // deep fp32 twiddles (levels 6..12)
  LevelTab lt;
  int acc = 0;
  for(int j=0;j<7;++j){
    int i = 6+j;
    lt.twoff[j]=acc; lt.ll[j]=lv[i]; lt.logh[j]=12-i;
    acc += 2*lv[i]*hv[i];
  }
  for(int j=7;j<13;++j){ lt.twoff[j]=0; lt.ll[j]=1; lt.logh[j]=0; }
  float* TWD = (float*)carve((size_t)acc*4);

  bfu* XPA = DTall;            // recon ping-pong (reuse, post-spectral)
  bfu* XPB = (bfu*)FTPa;

  // batch tables
  FwTab ftb; { int pc=0;
    for(int i=0;i<6;++i){ ftb.pcum[i]=pc; pc+=npv[i]; ftb.h[i]=hv[i]; ftb.np[i]=npv[i];
                          ftb.twF[i]=offF[i]; ftb.lvl[i]=lvl[i]; ftb.ftp[i]=ftpo[i]; }
    ftb.pcum[6]=pc; }
  DpTab dpb;
  for(int j=0;j<7;++j){ int i=6+j;
    dpb.lvl[j]=lvl[i]; dpb.ftp[j]=ftpo[i]; dpb.yt[j]=yto[i]; dpb.twD[j]=lt.twoff[j];
    dpb.h[j]=hv[i]; dpb.l[j]=lv[i]; dpb.lgh[j]=12-i; }
  PrTab prb;
  for(int i=0;i<13;++i){ prb.np[i]=npv[i]; prb.l[i]=lv[i]; prb.ftp[i]=ftpo[i]; prb.xa[i]=xao[i]; }
  MxTab mxb; int fTot=0;
  for(int i=0;i<13;++i){ mxb.fcum[i]=fTot; fTot+=lv[i]; mxb.h[i]=hv[i]; mxb.xa[i]=xao[i]; mxb.yt[i]=yto[i]; }
  IvTab ivb; int bxTot=0;
  for(int i=0;i<6;++i){ ivb.bxcum[i]=bxTot; bxTot+=hv[i]/128; ivb.h[i]=hv[i];
                        ivb.twF[i]=offF[i]; ivb.yt[i]=yto[i]; ivb.lvl[i]=lvl[i]; }

  // ---- setup ----
  k_sniff<<<dim3(1),256,0,stream>>>((const bfu*)x0, FLAG);
  k_cvt_small<<<dim3(1),256,0,stream>>>(d_in[7], d_in[8], d_in[9], d_in[10], d_in[11], d_in[12], CSM, FLAG);
  k_wtrans<<<dim3(128,6),256,0,stream>>>(wp, WT, FLAG);
  k_twgenF<<<dim3(4032,2),256,0,stream>>>(TWF, TWI);
  k_twgen<<<dim3(17,7),256,0,stream>>>(lt, TWD);

  // ---- phase 1: decompose chain (sequential) ----
  k_decomp0<<<dim3(hv[0]/32,16),256,0,stream>>>(x0, DTall+lvl[0], STall+lvl[0], CSM, hv[0], FLAG);
  for(int i=1;i<13;++i){
    int h = hv[i];
    const bfu* in = STall + lvl[i-1];
    bfu* dT = DTall + lvl[i];
    bfu* sT = STall + lvl[i];
    if(h >= 256){
      k_decompT_big<<<dim3(h/256,16,16),256,0,stream>>>(in, dT, sT, CSM, h);
    } else {
      int total = (h>=4) ? 16*16*(h>>2) : 256;
      k_decompT<<<dim3((total+255)/256),256,0,stream>>>(in, dT, sT, CSM, h, total);
    }
  }

  // ---- phase 2: forward DFTs, batched ----
  k_fwdft_all<<<dim3(ftb.pcum[6],16,4),256,0,stream>>>(DTall, STall, TWF, FTPa, ftb);
  k_fwdeep_all<<<dim3(16,2,7),256,0,stream>>>(DTall, STall, FTPa, TWD, dpb);

  // ---- phase 3: reduce + mode mixing, batched ----
  k_ftpred_all<<<dim3(512,13),256,0,stream>>>(FTPa, XAa, prb);
  k_modemix_all<<<dim3(fTot,8),256,0,stream>>>(XAa, WT, YTa, mxb);

  // ---- phase 4: inverse DFTs, batched ----
  k_invdft_all<<<dim3(bxTot,16,2),256,0,stream>>>(YTa, TWI, UdAll, UsAll, ivb);
  k_invdeep_all<<<dim3(16,2,7),256,0,stream>>>(YTa, UdAll, UsAll, TWD, dpb);

  // ---- phase 5: LN+GELU and reconstruction chain ----
  k_lngelu<<<dim3(16),128,0,stream>>>(STall + lvl[12], CSM, XPA);
  bfu* rin = XPA;
  for(int i=12;i>=0;--i){
    int h = hv[i];
    void* rout = (i==0) ? d_out : (void*)((rin==XPA) ? XPB : XPA);
    int tot = 16*h*16;
    k_recon<<<dim3((tot+255)/256),256,0,stream>>>(rin, UsAll+lvl[i], UdAll+lvl[i], CSM, rout, h, 12-i, (i==0)?1:0, FLAG);
    rin = (bfu*)rout;
  }
}

// Round 8
// 503.235 us; speedup vs baseline: 1.3829x; 1.0228x over previous
//
#include <hip/hip_runtime.h>
#include <math.h>

typedef unsigned short bfu;   // raw bf16 bits
typedef short bf16x8 __attribute__((ext_vector_type(8)));
typedef float f32x4 __attribute__((ext_vector_type(4)));

__device__ __forceinline__ float bs2f(bfu s){
  union{ unsigned int u; float f; } v; v.u = ((unsigned int)s) << 16; return v.f;
}
__device__ __forceinline__ bfu f2bs(float f){
  union{ float ff; unsigned int u; } v; v.ff = f;
  unsigned int u = v.u;
  unsigned int r = (u + 0x7fffu + ((u >> 16) & 1u)) >> 16;   // RNE
  return (bfu)r;
}

struct LevelTab { int twoff[13]; int ll[13]; int logh[13]; };
struct WPtrs { const void* p[6]; };
struct FwTab { int pcum[7]; int h[6]; int np[6]; int twF[6]; long lvl[6]; long ftp[6]; };
struct DpTab { long lvl[7]; long ftp[7]; long yt[7]; int twD[7]; int h[7]; int l[7]; int lgh[7]; };
struct PrTab { int np[13]; int l[13]; long ftp[13]; long xa[13]; };
struct Mx2   { int lv[13]; int h[13]; long xa[13]; long yt[13]; };
struct IvTab { int bxcum[6]; int h[6]; int twF[6]; long yt[6]; long lvl[6]; };

// ---------------- dtype sniff ------------------------------------------------
__global__ __launch_bounds__(256) void k_sniff(const bfu* __restrict__ x, int* __restrict__ flag){
  __shared__ int cnt;
  if(threadIdx.x==0) cnt = 0;
  __syncthreads();
  int c = 0;
  for(int j=threadIdx.x; j<4096; j+=256){
    bfu v = x[2*j];
    int e = (v>>7)&0xFF;
    if(e >= 0xC0) c++;
  }
  atomicAdd(&cnt, c);
  __syncthreads();
  if(threadIdx.x==0) flag[0] = (cnt > 64) ? 1 : 0;
}

// ---------------- small arrays -> bf16 ---------------------------------------
__global__ __launch_bounds__(256) void k_cvt_small(
    const void* lnw, const void* lnb, const void* ecs, const void* ecd,
    const void* rce, const void* rco, bfu* __restrict__ CSM, const int* __restrict__ FLAG){
  int f32 = FLAG[0];
  const void* src[6] = {ecs, ecd, rce, rco, lnw, lnb};
  int tid = threadIdx.x;
  for(int a=0; a<6; ++a)
    for(int j=tid; j<128; j+=256)
      CSM[a*128+j] = f32 ? f2bs(((const float*)src[a])[j]) : ((const bfu*)src[a])[j];
}

// ---------------- weight transpose: W[i][o][f] -> W2[w][f][o][i], bf16 -------
__global__ __launch_bounds__(256) void k_wtrans(WPtrs wp, bfu* __restrict__ W2, const int* __restrict__ FLAG){
  int f32 = FLAG[0];
  int o = blockIdx.x;          // 0..127
  int w = blockIdx.y;          // 0..5
  __shared__ bfu tile[64][130];   // [f][i]
  int tid = threadIdx.x;
  const void* src = wp.p[w];
  if(f32){
    const float* s = (const float*)src;
    #pragma unroll
    for(int it=0; it<8; ++it){
      int e = it*256 + tid;
      int i = e >> 4, fq = e & 15;
      float4 v = *reinterpret_cast<const float4*>(s + ((size_t)i*128 + o)*64 + fq*4);
      tile[fq*4+0][i] = f2bs(v.x);
      tile[fq*4+1][i] = f2bs(v.y);
      tile[fq*4+2][i] = f2bs(v.z);
      tile[fq*4+3][i] = f2bs(v.w);
    }
  } else {
    const bfu* s = (const bfu*)src;
    #pragma unroll
    for(int it=0; it<4; ++it){
      int e = it*256 + tid;
      int i = e >> 3, fq = e & 7;
      union{uint4 u; bfu x[8];} U;
      U.u = *reinterpret_cast<const uint4*>(s + ((size_t)i*128 + o)*64 + fq*8);
      #pragma unroll
      for(int j=0;j<8;++j) tile[fq*8+j][i] = U.x[j];
    }
  }
  __syncthreads();
  bfu* dst = W2 + (size_t)w*64*128*128 + (size_t)o*128;
  #pragma unroll
  for(int it=0; it<8; ++it){
    int e = it*256 + tid;
    int f = e >> 5, iq = e & 31;
    union{uint2 u; bfu x[4];} P;
    #pragma unroll
    for(int j=0;j<4;++j) P.x[j] = tile[f][iq*4+j];
    *reinterpret_cast<uint2*>(dst + (size_t)f*128*128 + iq*4) = P.u;
  }
}

// ---------------- bf16 twiddle matrices for MFMA levels 0..5 -----------------
__global__ __launch_bounds__(256) void k_twgenF(bfu* __restrict__ TWF, bfu* __restrict__ TWI){
  int e = blockIdx.x*256 + threadIdx.x;      // 0..1032191
  int kind = blockIdx.y;
  const int offs[7] = {0,524288,786432,917504,983040,1015808,1032192};
  int le = 5;
  #pragma unroll
  for(int i=0;i<6;++i){ if(e < offs[i+1]){ le = i; break; } }
  int rem = e - offs[le];
  int logh = 12 - le;
  int h = 1 << logh;
  int f, t, neg;
  if(kind==0){ int r = rem >> logh; t = rem & (h-1); f = (r<64)?r:(r-64); neg = (r>=64); }
  else       { t = rem >> 7; int f2 = rem & 127;     f = (f2<64)?f2:(f2-64); neg = (f2>=64); }
  int m = (f*t) & (h-1);
  float th = 6.283185307179586f * ((float)m / (float)h);
  float s, c; sincosf(th, &s, &c);
  float val = neg ? -s : c;
  if(kind==0) TWF[e] = f2bs(val); else TWI[e] = f2bs(val);
}

// ---------------- fp32 twiddles for deep levels ------------------------------
__global__ __launch_bounds__(256) void k_twgen(LevelTab lt, float* __restrict__ tw){
  int lev = blockIdx.y;
  int logh = lt.logh[lev];
  int h = 1 << logh;
  int l = lt.ll[lev];
  int tot = l*h;
  int idx = blockIdx.x*256 + threadIdx.x;
  if(idx >= tot) return;
  int t = idx & (h-1);
  int f = idx >> logh;
  int m = (f*t) & (h-1);
  float th = 6.283185307179586f * ((float)m / (float)h);
  float s, c; sincosf(th, &s, &c);
  tw[lt.twoff[lev] + idx] = c;
  tw[lt.twoff[lev] + tot + idx] = s;
}

// ---------------- level-0 decompose v3 ---------------------------------------
__global__ __launch_bounds__(256) void k_decomp0(
    const void* __restrict__ xin, bfu* __restrict__ dT, bfu* __restrict__ sT,
    const bfu* __restrict__ CSM, int h, const int* __restrict__ FLAG)
{
  int f32 = FLAG[0];
  __shared__ float ls[64][132];
  __shared__ bfu sdo[128][36];
  __shared__ bfu sso[128][36];
  __shared__ float Fd[16][8], Fs[16][8];
  int tid = threadIdx.x;
  if(tid < 128){ Fs[tid>>3][tid&7] = bs2f(CSM[tid]); Fd[tid>>3][tid&7] = bs2f(CSM[128+tid]); }
  int b = blockIdx.y;
  int t0in = blockIdx.x * 64;
  if(f32){
    const float* src = (const float*)xin + ((size_t)b*2*h + t0in)*128;
    #pragma unroll
    for(int it=0; it<8; ++it){
      int e = it*256 + tid;
      int row = e>>5, cq = e&31;
      float4 v = *reinterpret_cast<const float4*>(src + (size_t)row*128 + cq*4);
      ls[row][cq*4+0]=v.x; ls[row][cq*4+1]=v.y; ls[row][cq*4+2]=v.z; ls[row][cq*4+3]=v.w;
    }
  } else {
    const bfu* src = (const bfu*)xin + ((size_t)b*2*h + t0in)*128;
    #pragma unroll
    for(int it=0; it<4; ++it){
      int e = it*256 + tid;
      int row = e>>4, cq = e&15;
      union{uint4 u; bfu x[8];} U;
      U.u = *reinterpret_cast<const uint4*>(src + (size_t)row*128 + cq*8);
      #pragma unroll
      for(int j=0;j<8;++j) ls[row][cq*8+j] = bs2f(U.x[j]);
    }
  }
  __syncthreads();
  int g = tid>>7, ch = tid&127;
  int c = ch>>3, kp = ch&7;
  float fdE[8], fdO[8], fsE[8], fsO[8];
  #pragma unroll
  for(int j=0;j<8;++j){ fdE[j]=Fd[j][kp]; fdO[j]=Fd[8+j][kp]; fsE[j]=Fs[j][kp]; fsO[j]=Fs[8+j][kp]; }
  union{ uint2 u; bfu x[4]; } Dq, Sq;
  #pragma unroll
  for(int tl=0; tl<16; ++tl){
    int rl = 2*(g*16+tl);
    const float* ev = &ls[rl][c*8];
    const float* od = &ls[rl+1][c*8];
    float d=0.f, s=0.f;
    #pragma unroll
    for(int j=0;j<8;++j){
      d += ev[j]*fdE[j] + od[j]*fdO[j];
      s += ev[j]*fsE[j] + od[j]*fsO[j];
    }
    Dq.x[tl&3] = f2bs(d); Sq.x[tl&3] = f2bs(s);
    if((tl&3)==3){
      int tb = g*16 + (tl & ~3);
      *reinterpret_cast<uint2*>(&sdo[ch][tb]) = Dq.u;
      *reinterpret_cast<uint2*>(&sso[ch][tb]) = Sq.u;
    }
  }
  __syncthreads();
  size_t obase = (size_t)b*128*h + (t0in>>1);
  #pragma unroll
  for(int it=0; it<4; ++it){
    int e = it*256 + tid;
    int r = e >> 3, kq = e & 7;
    union{uint2 u; bfu x[4];} P;
    #pragma unroll
    for(int j=0;j<4;++j) P.x[j] = sdo[r][kq*4+j];
    *reinterpret_cast<uint2*>(dT + obase + (size_t)r*h + kq*4) = P.u;
  }
  #pragma unroll
  for(int it=0; it<4; ++it){
    int e = it*256 + tid;
    int r = e >> 3, kq = e & 7;
    union{uint2 u; bfu x[4];} P;
    #pragma unroll
    for(int j=0;j<4;++j) P.x[j] = sso[r][kq*4+j];
    *reinterpret_cast<uint2*>(sT + obase + (size_t)r*h + kq*4) = P.u;
  }
}

// ---------------- transposed decompose, big levels (h >= 256) ----------------
__global__ __launch_bounds__(256) void k_decompT_big(
    const bfu* __restrict__ inT, bfu* __restrict__ dT, bfu* __restrict__ sT,
    const bfu* __restrict__ CSM, int h)
{
  __shared__ float Fd[16][8], Fs[16][8];
  int tid = threadIdx.x;
  if(tid < 128){ Fs[tid>>3][tid&7] = bs2f(CSM[tid]); Fd[tid>>3][tid&7] = bs2f(CSM[128+tid]); }
  __syncthreads();
  int tt0 = blockIdx.x * 256;
  int b = blockIdx.y, c = blockIdx.z;
  int kp = tid >> 5, tq = tid & 31;
  float fdE[8], fdO[8], fsE[8], fsO[8];
  #pragma unroll
  for(int k=0;k<8;++k){ fdE[k]=Fd[k][kp]; fdO[k]=Fd[8+k][kp]; fsE[k]=Fs[k][kp]; fsO[k]=Fs[8+k][kp]; }
  const bfu* base = inT + ((size_t)b*128 + c*8)*(size_t)(2*h) + (size_t)2*tt0 + tq*16;
  union{uint4 u[2]; bfu x[16];} E[8];
  #pragma unroll
  for(int k=0;k<8;++k){
    E[k].u[0] = *reinterpret_cast<const uint4*>(base + (size_t)k*(2*h));
    E[k].u[1] = *reinterpret_cast<const uint4*>(base + (size_t)k*(2*h) + 8);
  }
  union{uint4 u; bfu x[8];} Od, Os;
  #pragma unroll
  for(int to=0; to<8; ++to){
    float d=0.f, s=0.f;
    #pragma unroll
    for(int k=0;k<8;++k){
      float ev = bs2f(E[k].x[2*to]), od = bs2f(E[k].x[2*to+1]);
      d += ev*fdE[k] + od*fdO[k];
      s += ev*fsE[k] + od*fsO[k];
    }
    Od.x[to] = f2bs(d); Os.x[to] = f2bs(s);
  }
  size_t ob = ((size_t)b*128 + c*8 + kp)*h + tt0 + tq*8;
  *reinterpret_cast<uint4*>(dT + ob) = Od.u;
  *reinterpret_cast<uint4*>(sT + ob) = Os.u;
}

// ---------------- transposed decompose (small levels) ------------------------
__global__ __launch_bounds__(256) void k_decompT(
    const bfu* __restrict__ inT, bfu* __restrict__ dT, bfu* __restrict__ sT,
    const bfu* __restrict__ CSM, int h, int total)
{
  __shared__ float Fd[16][8], Fs[16][8];
  int tid = threadIdx.x;
  if(tid < 128){ Fs[tid>>3][tid&7] = bs2f(CSM[tid]); Fd[tid>>3][tid&7] = bs2f(CSM[128+tid]); }
  __syncthreads();
  int idx = blockIdx.x*256 + tid;
  if(idx >= total) return;
  if(h >= 4){
    int nto = h>>2;
    int to = idx & (nto-1);
    int bc = idx / nto;
    int c = bc & 15, b = bc >> 4;
    const bfu* base = inT + ((size_t)b*128 + c*8)*(size_t)(2*h) + to*8;
    float d8[4][8] = {}, s8[4][8] = {};
    #pragma unroll
    for(int k=0;k<8;++k){
      union{uint4 u; bfu x[8];} U;
      U.u = *reinterpret_cast<const uint4*>(base + (size_t)k*(2*h));
      const float* fdE = Fd[k]; const float* fdO = Fd[8+k];
      const float* fsE = Fs[k]; const float* fsO = Fs[8+k];
      #pragma unroll
      for(int tl=0; tl<4; ++tl){
        float ev = bs2f(U.x[2*tl]), od = bs2f(U.x[2*tl+1]);
        #pragma unroll
        for(int kp=0;kp<8;++kp){
          d8[tl][kp] += ev*fdE[kp] + od*fdO[kp];
          s8[tl][kp] += ev*fsE[kp] + od*fsO[kp];
        }
      }
    }
    #pragma unroll
    for(int kp=0;kp<8;++kp){
      union{uint2 u; bfu x[4];} Od, Os;
      #pragma unroll
      for(int tl=0;tl<4;++tl){ Od.x[tl]=f2bs(d8[tl][kp]); Os.x[tl]=f2bs(s8[tl][kp]); }
      size_t ob = ((size_t)b*128 + c*8 + kp)*h + to*4;
      *reinterpret_cast<uint2*>(dT + ob) = Od.u;
      *reinterpret_cast<uint2*>(sT + ob) = Os.u;
    }
  } else {
    int c = idx & 15, b = idx >> 4;
    const bfu* base = inT + ((size_t)b*128 + c*8)*(size_t)(2*h);
    for(int tl=0; tl<h; ++tl){
      float d8[8]={}, s8[8]={};
      for(int k=0;k<8;++k){
        float ev = bs2f(base[(size_t)k*2*h + 2*tl]);
        float od = bs2f(base[(size_t)k*2*h + 2*tl+1]);
        #pragma unroll
        for(int kp=0;kp<8;++kp){
          d8[kp] += ev*Fd[k][kp] + od*Fd[8+k][kp];
          s8[kp] += ev*Fs[k][kp] + od*Fs[8+k][kp];
        }
      }
      for(int kp=0;kp<8;++kp){
        size_t ob = ((size_t)b*128 + c*8 + kp)*h + tl;
        dT[ob] = f2bs(d8[kp]); sT[ob] = f2bs(s8[kp]);
      }
    }
  }
}

// ---------------- MFMA forward DFT, batched levels 0..5 ----------------------
__global__ __launch_bounds__(256) void k_fwdft_all(
    const bfu* __restrict__ DTall, const bfu* __restrict__ STall,
    const bfu* __restrict__ TWF, float* __restrict__ FTPa, FwTab ft)
{
  int gp = blockIdx.x, b = blockIdx.y;
  int sig = blockIdx.z >> 1, rh = blockIdx.z & 1;
  int lev = 0;
  for(int i=5;i>0;--i){ if(gp >= ft.pcum[i]){ lev = i; break; } }
  int p = gp - ft.pcum[lev];
  int h = ft.h[lev];
  int Kpart = h / ft.np[lev];
  const bfu* SIG = (sig ? STall : DTall) + ft.lvl[lev] + (size_t)b*128*h;
  const bfu* TWr = TWF + ft.twF[lev] + (size_t)(rh*64)*h;
  __shared__ bfu lsA[64*72];
  __shared__ bfu lsB[128*72];
  int tid = threadIdx.x;
  int wave = tid>>6, lane = tid&63;
  int mh = (wave>>1)*32, nh = (wave&1)*64;
  int ml = lane&15, q = lane>>4;
  f32x4 acc[2][4];
  #pragma unroll
  for(int i=0;i<2;++i){
    #pragma unroll
    for(int j=0;j<4;++j) acc[i][j] = (f32x4)0.f;
  }
  int k0base = p*Kpart;
  for(int kc=0; kc<Kpart; kc+=64){
    int k0 = k0base + kc;
    #pragma unroll
    for(int it=0; it<2; ++it){
      int slot = it*256 + tid;
      int row = slot>>3, kq = slot&7;
      *reinterpret_cast<uint4*>(&lsA[row*72 + kq*8]) =
        *reinterpret_cast<const uint4*>(&TWr[(size_t)row*h + k0 + kq*8]);
    }
    #pragma unroll
    for(int it=0; it<4; ++it){
      int slot = it*256 + tid;
      int row = slot>>3, kq = slot&7;
      *reinterpret_cast<uint4*>(&lsB[row*72 + kq*8]) =
        *reinterpret_cast<const uint4*>(&SIG[(size_t)row*h + k0 + kq*8]);
    }
    __syncthreads();
    #pragma unroll
    for(int kk=0; kk<64; kk+=32){
      bf16x8 af[2], bfr[4];
      #pragma unroll
      for(int mi=0;mi<2;++mi)
        af[mi] = *reinterpret_cast<const bf16x8*>(&lsA[(mh+mi*16+ml)*72 + kk + q*8]);
      #pragma unroll
      for(int ni=0;ni<4;++ni)
        bfr[ni] = *reinterpret_cast<const bf16x8*>(&lsB[(nh+ni*16+ml)*72 + kk + q*8]);
      #pragma unroll
      for(int mi=0;mi<2;++mi){
        #pragma unroll
        for(int ni=0;ni<4;++ni)
          acc[mi][ni] = __builtin_amdgcn_mfma_f32_16x16x32_bf16(af[mi], bfr[ni], acc[mi][ni], 0,0,0);
      }
    }
    __syncthreads();
  }
  float* dst = FTPa + ft.ftp[lev] + (((size_t)p*2 + sig)*16 + b)*16384;
  #pragma unroll
  for(int mi=0;mi<2;++mi){
    #pragma unroll
    for(int ni=0;ni<4;++ni){
      int row = rh*64 + mh + mi*16 + q*4;
      int col = nh + ni*16 + ml;
      #pragma unroll
      for(int r=0;r<4;++r)
        dst[(size_t)(row+r)*128 + col] = acc[mi][ni][r];
    }
  }
}

// ---------------- deep forward DFT, batched levels 6..12 ---------------------
__global__ __launch_bounds__(256) void k_fwdeep_all(
    const bfu* __restrict__ DTall, const bfu* __restrict__ STall,
    float* __restrict__ FTPa, const float* __restrict__ TWD, DpTab dp)
{
  int b = blockIdx.x, sig = blockIdx.y, j = blockIdx.z;
  int h = dp.h[j], l = dp.l[j], logh = dp.lgh[j];
  const bfu* src = (sig? STall : DTall) + dp.lvl[j] + (size_t)b*128*h;
  float* dst = FTPa + dp.ftp[j] + ((size_t)sig*16 + b)*16384;
  const float* TWc = TWD + dp.twD[j];
  __shared__ float s_sig[128*65];
  __shared__ float s_twc[33*64];
  __shared__ float s_tws[33*64];
  int tid = threadIdx.x;
  int hp = h + 1;
  for(int e = tid; e < 128*h; e += 256){
    int ch = e >> logh, t = e & (h-1);
    s_sig[ch*hp + t] = bs2f(src[e]);
  }
  int lh = l*h;
  const float* TWs = TWc + (size_t)lh;
  for(int e = tid; e < lh; e += 256){ s_twc[e] = TWc[e]; s_tws[e] = TWs[e]; }
  __syncthreads();
  for(int idx = tid; idx < l*128; idx += 256){
    int f = idx >> 7, ch = idx & 127;
    const float* sp = &s_sig[ch*hp];
    const float* cp = &s_twc[f*h];
    const float* zp = &s_tws[f*h];
    float re = 0.f, im = 0.f;
    for(int t=0; t<h; ++t){ float v = sp[t]; re += v*cp[t]; im -= v*zp[t]; }
    dst[(size_t)f*128 + ch] = re;
    dst[(size_t)(64+f)*128 + ch] = im;
  }
}

// ---------------- FTP reduce + A-matrix build, batched all levels ------------
__global__ __launch_bounds__(256) void k_ftpred_all(
    const float* __restrict__ FTPa, bfu* __restrict__ XAa, PrTab pt)
{
  int lev = blockIdx.y;
  int e = blockIdx.x*256 + threadIdx.x;     // 0..131071
  const size_t PS = (size_t)2*16*128*128;
  int ch4 = e & 31;
  int row = (e>>5) & 127;
  int b   = (e>>12) & 15;
  int sig = e>>16;
  int f = row & 63, im = row >> 6;
  if(f >= pt.l[lev]) return;
  const float* F = FTPa + pt.ftp[lev];
  int np = pt.np[lev];
  size_t src = (((size_t)sig*16 + b)*128 + row)*128 + (size_t)ch4*4;
  f32x4 v = *reinterpret_cast<const f32x4*>(&F[src]);
  for(int p=1;p<np;++p)
    v += *reinterpret_cast<const f32x4*>(&F[src + (size_t)p*PS]);
  int ch = ch4*4;
  union{ uint2 u; bfu x[4]; } P1, P3;
  #pragma unroll
  for(int j=0;j<4;++j){
    float vj = v[j];
    P1.x[j] = f2bs(im ? -vj : vj);
    P3.x[j] = f2bs(vj);
  }
  bfu* XA = XAa + pt.xa[lev];
  size_t base = (size_t)f*32*512;
  *reinterpret_cast<uint2*>(&XA[base + (size_t)b*512 + sig*256 + im*128 + ch]) = P1.u;
  *reinterpret_cast<uint2*>(&XA[base + (size_t)(16+b)*512 + sig*256 + (1-im)*128 + ch]) = P3.u;
}

// ---------------- MFMA mode mixing: level-loop, reg-hoisted weights ----------
// grid (64 f, 8 og), block 256 = 4 waves: wid = (part<<1)|m.
// Weights in registers (loaded once). XA slice LDS-staged per level.
// Output Y'[u][b][fo][ch] (ch innermost -> 32B-run coalesced writes).
__global__ __launch_bounds__(256) void k_modemix_lvl(
    const bfu* __restrict__ XAa, const bfu* __restrict__ W2,
    bfu* __restrict__ YTp, Mx2 mt)
{
  int f = blockIdx.x;
  int obase = blockIdx.y * 16;
  int tid = threadIdx.x;
  int wid = tid>>6, lane = tid&63;
  int m = wid & 1, part = wid >> 1;
  int ml = lane & 15, q = lane >> 4;
  const size_t WSZ = (size_t)64*128*128;
  const bfu* Wb = W2 + ((size_t)f*128 + obase + ml)*128 + q*8;
  bf16x8 wf[16];
  if(part == 0){
    #pragma unroll
    for(int ks=0; ks<16; ++ks)
      wf[ks] = *reinterpret_cast<const bf16x8*>(Wb + (size_t)(ks>>2)*WSZ + (ks&3)*32);
  } else {
    #pragma unroll
    for(int ks=0; ks<8; ++ks)
      wf[ks] = *reinterpret_cast<const bf16x8*>(Wb + (size_t)(4 + (ks>>2))*WSZ + (ks&3)*32);
  }
  __shared__ bfu lsA[32*520];      // stride 520 -> 2-way banks, 16B aligned
  for(int lev=0; lev<13; ++lev){
    if(f >= mt.lv[lev]) continue;
    const bfu* Asrc = XAa + mt.xa[lev] + (size_t)f*16384;
    #pragma unroll
    for(int it=0; it<8; ++it){
      int slot = it*256 + tid;       // 2048 uint4 = 32 rows x 64 kq
      int row = slot>>6, kq = slot&63;
      *reinterpret_cast<uint4*>(&lsA[row*520 + kq*8]) =
        *reinterpret_cast<const uint4*>(&Asrc[(size_t)row*512 + kq*8]);
    }
    __syncthreads();
    const bfu* Ar = &lsA[(m*16+ml)*520 + q*8];
    f32x4 acc = (f32x4)0.f;
    if(part == 0){
      #pragma unroll
      for(int ks=0; ks<16; ++ks){
        bf16x8 A = *reinterpret_cast<const bf16x8*>(Ar + ks*32);
        acc = __builtin_amdgcn_mfma_f32_16x16x32_bf16(A, wf[ks], acc, 0,0,0);
      }
    } else {
      #pragma unroll
      for(int ks=0; ks<8; ++ks){
        bf16x8 A = *reinterpret_cast<const bf16x8*>(Ar + ks*32);
        acc = __builtin_amdgcn_mfma_f32_16x16x32_bf16(A, wf[ks], acc, 0,0,0);
      }
    }
    int h = mt.h[lev];
    bool edge = (f==0) || (2*f == h);
    float sc = edge ? 1.0f/(float)h : 2.0f/(float)h;
    int fo = m ? (64+f) : f;
    bfu* dst = YTp + mt.yt[lev] + (part ? (size_t)16*128*128 : 0);
    #pragma unroll
    for(int r=0;r<4;++r){
      int b = q*4 + r;
      float val = acc[r]*sc;
      if(m && edge) val = 0.f;
      dst[((size_t)b*128 + fo)*128 + obase + ml] = f2bs(val);
    }
    __syncthreads();
  }
}

// ---------------- YT transpose: Y'[u][b][fo][ch] -> Y[u][b][ch][fo] ----------
// grid (16 b, 2 u, 13 lev)
__global__ __launch_bounds__(256) void k_yttrans(
    const bfu* __restrict__ YTp, bfu* __restrict__ YT2, Mx2 mt)
{
  int b = blockIdx.x, u = blockIdx.y, lev = blockIdx.z;
  const bfu* src = YTp + mt.yt[lev] + ((size_t)u*16 + b)*16384;
  bfu* dst = YT2 + mt.yt[lev] + ((size_t)u*16 + b)*16384;
  __shared__ bfu tile[128][130];
  int tid = threadIdx.x;
  #pragma unroll
  for(int it=0; it<8; ++it){
    int slot = it*256 + tid;        // 2048 uint4 = 128 fo x 16 kq
    int fo = slot>>4, kq = slot&15;
    union{uint4 u4; bfu x[8];} U;
    U.u4 = *reinterpret_cast<const uint4*>(&src[(size_t)fo*128 + kq*8]);
    #pragma unroll
    for(int j=0;j<8;++j) tile[kq*8+j][fo] = U.x[j];
  }
  __syncthreads();
  #pragma unroll
  for(int it=0; it<8; ++it){
    int slot = it*256 + tid;        // 2048 uint4 = 128 ch x 16 kq
    int ch = slot>>4, kq = slot&15;
    union{uint4 u4; bfu x[8];} P;
    #pragma unroll
    for(int j=0;j<8;++j) P.x[j] = tile[ch][kq*8+j];
    *reinterpret_cast<uint4*>(&dst[(size_t)ch*128 + kq*8]) = P.u4;
  }
}

// ---------------- MFMA inverse DFT, batched levels 0..5 ----------------------
__global__ __launch_bounds__(256) void k_invdft_all(
    const bfu* __restrict__ YTa, const bfu* __restrict__ TWI,
    bfu* __restrict__ UdAll, bfu* __restrict__ UsAll, IvTab iv)
{
  int x = blockIdx.x, b = blockIdx.y, u = blockIdx.z;
  int lev = 0;
  for(int i=5;i>0;--i){ if(x >= iv.bxcum[i]){ lev = i; break; } }
  int bx = x - iv.bxcum[lev];
  int h = iv.h[lev];
  bfu* outp = (u ? UsAll : UdAll) + iv.lvl[lev];
  const bfu* Y = YTa + iv.yt[lev] + ((size_t)u*16 + b)*16384;
  const bfu* TWIl = TWI + iv.twF[lev];
  int t0 = bx*128;
  __shared__ bfu lsA[128*136];
  __shared__ bfu lsB[128*136];
  int tid = threadIdx.x;
  #pragma unroll
  for(int it=0; it<8; ++it){
    int slot = it*256 + tid;
    int row = slot>>4, kq = slot&15;
    *reinterpret_cast<uint4*>(&lsA[row*136 + kq*8]) =
      *reinterpret_cast<const uint4*>(&TWIl[(size_t)(t0+row)*128 + kq*8]);
    *reinterpret_cast<uint4*>(&lsB[row*136 + kq*8]) =
      *reinterpret_cast<const uint4*>(&Y[(size_t)row*128 + kq*8]);
  }
  __syncthreads();
  int wave = tid>>6, lane = tid&63;
  int mh = (wave>>1)*64, nh = (wave&1)*64;
  int ml = lane&15, q = lane>>4;
  f32x4 acc[4][4];
  #pragma unroll
  for(int i=0;i<4;++i){
    #pragma unroll
    for(int j=0;j<4;++j) acc[i][j] = (f32x4)0.f;
  }
  #pragma unroll
  for(int kk=0; kk<128; kk+=32){
    bf16x8 af[4], bfr[4];
    #pragma unroll
    for(int mi=0;mi<4;++mi)
      af[mi] = *reinterpret_cast<const bf16x8*>(&lsA[(mh+mi*16+ml)*136 + kk + q*8]);
    #pragma unroll
    for(int ni=0;ni<4;++ni)
      bfr[ni] = *reinterpret_cast<const bf16x8*>(&lsB[(nh+ni*16+ml)*136 + kk + q*8]);
    #pragma unroll
    for(int mi=0;mi<4;++mi){
      #pragma unroll
      for(int ni=0;ni<4;++ni)
        acc[mi][ni] = __builtin_amdgcn_mfma_f32_16x16x32_bf16(af[mi], bfr[ni], acc[mi][ni], 0,0,0);
    }
  }
  #pragma unroll
  for(int mi=0;mi<4;++mi){
    #pragma unroll
    for(int ni=0;ni<4;++ni){
      int row = mh + mi*16 + q*4;
      int col = nh + ni*16 + ml;
      #pragma unroll
      for(int r=0;r<4;++r)
        outp[((size_t)b*h + t0+row+r)*128 + col] = f2bs(acc[mi][ni][r]);
    }
  }
}

// ---------------- deep inverse DFT, batched levels 6..12 ---------------------
__global__ __launch_bounds__(256) void k_invdeep_all(
    const bfu* __restrict__ YTa, bfu* __restrict__ UdAll, bfu* __restrict__ UsAll,
    const float* __restrict__ TWD, DpTab dp)
{
  int b = blockIdx.x, u = blockIdx.y, j = blockIdx.z;
  int h = dp.h[j], l = dp.l[j];
  bfu* outp = (u? UsAll : UdAll) + dp.lvl[j] + (size_t)b*h*128;
  const bfu* Y = YTa + dp.yt[j] + ((size_t)u*16 + b)*16384;
  const float* TWc = TWD + dp.twD[j];
  __shared__ float s_yr[128*66];
  __shared__ float s_yi[128*66];
  __shared__ float s_twc[33*64];
  __shared__ float s_tws[33*64];
  int tid = threadIdx.x;
  #pragma unroll
  for(int it=0; it<8; ++it){
    int slot = it*256 + tid;
    int ch = slot >> 4, kq = slot & 15;
    union{uint4 u4; bfu x[8];} U;
    U.u4 = *reinterpret_cast<const uint4*>(&Y[(size_t)ch*128 + kq*8]);
    if(kq < 8){
      #pragma unroll
      for(int jj=0;jj<8;++jj) s_yr[ch*66 + kq*8 + jj] = bs2f(U.x[jj]);
    } else {
      #pragma unroll
      for(int jj=0;jj<8;++jj) s_yi[ch*66 + (kq-8)*8 + jj] = bs2f(U.x[jj]);
    }
  }
  int lh = l*h;
  const float* TWs = TWc + (size_t)lh;
  for(int e = tid; e < lh; e += 256){ s_twc[e] = TWc[e]; s_tws[e] = TWs[e]; }
  __syncthreads();
  for(int idx = tid; idx < h*128; idx += 256){
    int t = idx >> 7, ch = idx & 127;
    const float* yr = &s_yr[ch*66];
    const float* yi = &s_yi[ch*66];
    float a = 0.f;
    for(int f=0; f<l; ++f)
      a += yr[f]*s_twc[f*h + t] - yi[f]*s_tws[f*h + t];
    outp[idx] = f2bs(a);
  }
}

// ---------------- LayerNorm + exact GELU on (16,1,128) -----------------------
__global__ __launch_bounds__(128) void k_lngelu(
    const bfu* __restrict__ xin, const bfu* __restrict__ CSM, bfu* __restrict__ xout)
{
  int b = blockIdx.x, tid = threadIdx.x;
  float v = bs2f(xin[b*128 + tid]);
  float s1 = v, s2 = v*v;
  #pragma unroll
  for(int o=32; o; o>>=1){ s1 += __shfl_down(s1,o); s2 += __shfl_down(s2,o); }
  __shared__ float red[2][2];
  int w = tid >> 6;
  if((tid & 63) == 0){ red[w][0]=s1; red[w][1]=s2; }
  __syncthreads();
  float m  = (red[0][0]+red[1][0]) * (1.0f/128.0f);
  float ms = (red[0][1]+red[1][1]) * (1.0f/128.0f);
  float var = ms - m*m;
  float xn = (v - m) * rsqrtf(var + 1e-5f) * bs2f(CSM[512+tid]) + bs2f(CSM[640+tid]);
  float g = 0.5f * xn * (1.0f + erff(xn * 0.70710678118654752f));
  xout[b*128 + tid] = f2bs(g);
}

// ---------------- reconstruction step ([t][ch] layout) -----------------------
__global__ __launch_bounds__(256) void k_recon(
    const bfu* __restrict__ xin, const bfu* __restrict__ usp, const bfu* __restrict__ udp,
    const bfu* __restrict__ CSM, void* __restrict__ xout, int h, int logh,
    int is_final, const int* __restrict__ FLAG)
{
  int f32 = is_final ? FLAG[0] : 0;
  __shared__ float Fe[16][8], Fo[16][8];
  int tid = threadIdx.x;
  if(tid < 128){ Fe[tid>>3][tid&7] = bs2f(CSM[256+tid]); Fo[tid>>3][tid&7] = bs2f(CSM[384+tid]); }
  __syncthreads();
  int idx = blockIdx.x*256 + tid;
  if(idx >= 16*h*16) return;
  int c  = idx & 15;
  int bt = idx >> 4;
  int t  = bt & (h-1);
  int b  = bt >> logh;
  size_t base = (((size_t)bt) << 7) + (c<<3);
  union{ uint4 u; bfu x[8]; } X, U, D;
  X.u = *reinterpret_cast<const uint4*>(xin + base);
  U.u = *reinterpret_cast<const uint4*>(usp + base);
  D.u = *reinterpret_cast<const uint4*>(udp + base);
  float y[16];
  #pragma unroll
  for(int j=0;j<8;++j){ y[j] = bs2f(X.x[j]) + bs2f(U.x[j]); y[8+j] = bs2f(D.x[j]); }
  float e8[8] = {0,0,0,0,0,0,0,0}, o8[8] = {0,0,0,0,0,0,0,0};
  #pragma unroll
  for(int j=0;j<16;++j){
    float v = y[j];
    #pragma unroll
    for(int k=0;k<8;++k){ e8[k] += v*Fe[j][k]; o8[k] += v*Fo[j][k]; }
  }
  size_t ob = (((size_t)(b*(h<<1) + (t<<1))) << 7) + (c<<3);
  if(f32){
    float* po = (float*)xout;
    *reinterpret_cast<float4*>(po + ob)       = make_float4(e8[0],e8[1],e8[2],e8[3]);
    *reinterpret_cast<float4*>(po + ob + 4)   = make_float4(e8[4],e8[5],e8[6],e8[7]);
    *reinterpret_cast<float4*>(po + ob + 128) = make_float4(o8[0],o8[1],o8[2],o8[3]);
    *reinterpret_cast<float4*>(po + ob + 132) = make_float4(o8[4],o8[5],o8[6],o8[7]);
  } else {
    union{ uint4 u; bfu x[8]; } Oe, Oo;
    #pragma unroll
    for(int k=0;k<8;++k){ Oe.x[k] = f2bs(e8[k]); Oo.x[k] = f2bs(o8[k]); }
    bfu* po = (bfu*)xout;
    *reinterpret_cast<uint4*>(po + ob)       = Oe.u;
    *reinterpret_cast<uint4*>(po + ob + 128) = Oo.u;
  }
}

// ============================================================================
extern "C" void kernel_launch(void* const* d_in, const int* in_sizes, int n_in,
                              void* d_out, int out_size, void* d_ws, size_t ws_size,
                              hipStream_t stream)
{
  (void)in_sizes; (void)n_in; (void)out_size; (void)ws_size;
  const void* x0 = d_in[0];
  WPtrs wp;
  for(int w=0;w<6;++w) wp.p[w] = d_in[1+w];

  char* ws = (char*)d_ws;
  size_t off = 0;
  auto carve = [&](size_t bytes)->char*{
    char* p = ws + off; off += (bytes + 255) & ~(size_t)255; return p; };

  // level params
  int hv[13], lv[13], npv[13];
  const int offF[6] = {0,524288,786432,917504,983040,1015808};
  for(int i=0;i<13;++i){
    hv[i] = 4096 >> i;
    int l = hv[i]/2 + 1;
    lv[i] = (l < 64) ? l : 64;
    npv[i] = (i < 6) ? ((hv[i]/1024 > 0) ? hv[i]/1024 : 1) : 1;   // 4,2,1,1,1,1,...
  }
  long lvl[13]; long aTot = 0;
  for(int i=0;i<13;++i){ lvl[i] = aTot; aTot += (long)16*128*hv[i]; }
  long ftpo[13]; long fsl = 0;
  for(int i=0;i<13;++i){ ftpo[i] = fsl*524288L; fsl += npv[i]; }
  long xao[13]; long xsl = 0;
  for(int i=0;i<13;++i){ xao[i] = xsl; xsl += (long)lv[i]*16384; }
  long yto[13];
  for(int i=0;i<13;++i) yto[i] = (long)i*524288;

  int* FLAG = (int*)carve(256);
  bfu* CSM  = (bfu*)carve(2048);
  bfu* STall = (bfu*)carve((size_t)aTot*2);
  bfu* DTall = (bfu*)carve((size_t)aTot*2);
  bfu* UdAll = (bfu*)carve((size_t)aTot*2);
  bfu* UsAll = (bfu*)carve((size_t)aTot*2);
  bfu* WT   = (bfu*)carve((size_t)6*64*128*128*2);
  bfu* XAa  = (bfu*)carve((size_t)xsl*2);
  bfu* YTp  = (bfu*)carve((size_t)13*524288*2);    // Y'[u][b][fo][ch]
  bfu* YT2  = (bfu*)carve((size_t)13*524288*2);    // Y[u][b][ch][fo]
  bfu* TWF  = (bfu*)carve((size_t)1032192*2);
  bfu* TWI  = (bfu*)carve((size_t)1032192*2);
  float* FTPa = (float*)carve((size_t)fsl*524288*4);

  // deep fp32 twiddles (levels 6..12)
  LevelTab lt;
  int acc = 0;
  for(int j=0;j<7;++j){
    int i = 6+j;
    lt.twoff[j]=acc; lt.ll[j]=lv[i]; lt.logh[j]=12-i;
    acc += 2*lv[i]*hv[i];
  }
  for(int j=7;j<13;++j){ lt.twoff[j]=0; lt.ll[j]=1; lt.logh[j]=0; }
  float* TWD = (float*)carve((size_t)acc*4);

  bfu* XPA = DTall;            // recon ping-pong (reuse, post-spectral)
  bfu* XPB = (bfu*)FTPa;

  // batch tables
  FwTab ftb; { int pc=0;
    for(int i=0;i<6;++i){ ftb.pcum[i]=pc; pc+=npv[i]; ftb.h[i]=hv[i]; ftb.np[i]=npv[i];
                          ftb.twF[i]=offF[i]; ftb.lvl[i]=lvl[i]; ftb.ftp[i]=ftpo[i]; }
    ftb.pcum[6]=pc; }
  DpTab dpb;
  for(int j=0;j<7;++j){ int i=6+j;
    dpb.lvl[j]=lvl[i]; dpb.ftp[j]=ftpo[i]; dpb.yt[j]=yto[i]; dpb.twD[j]=lt.twoff[j];
    dpb.h[j]=hv[i]; dpb.l[j]=lv[i]; dpb.lgh[j]=12-i; }
  PrTab prb;
  for(int i=0;i<13;++i){ prb.np[i]=npv[i]; prb.l[i]=lv[i]; prb.ftp[i]=ftpo[i]; prb.xa[i]=xao[i]; }
  Mx2 mxb;
  for(int i=0;i<13;++i){ mxb.lv[i]=lv[i]; mxb.h[i]=hv[i]; mxb.xa[i]=xao[i]; mxb.yt[i]=yto[i]; }
  IvTab ivb; int bxTot=0;
  for(int i=0;i<6;++i){ ivb.bxcum[i]=bxTot; bxTot+=hv[i]/128; ivb.h[i]=hv[i];
                        ivb.twF[i]=offF[i]; ivb.yt[i]=yto[i]; ivb.lvl[i]=lvl[i]; }

  // ---- setup ----
  k_sniff<<<dim3(1),256,0,stream>>>((const bfu*)x0, FLAG);
  k_cvt_small<<<dim3(1),256,0,stream>>>(d_in[7], d_in[8], d_in[9], d_in[10], d_in[11], d_in[12], CSM, FLAG);
  k_wtrans<<<dim3(128,6),256,0,stream>>>(wp, WT, FLAG);
  k_twgenF<<<dim3(4032,2),256,0,stream>>>(TWF, TWI);
  k_twgen<<<dim3(17,7),256,0,stream>>>(lt, TWD);

  // ---- phase 1: decompose chain (sequential) ----
  k_decomp0<<<dim3(hv[0]/32,16),256,0,stream>>>(x0, DTall+lvl[0], STall+lvl[0], CSM, hv[0], FLAG);
  for(int i=1;i<13;++i){
    int h = hv[i];
    const bfu* in = STall + lvl[i-1];
    bfu* dT = DTall + lvl[i];
    bfu* sT = STall + lvl[i];
    if(h >= 256){
      k_decompT_big<<<dim3(h/256,16,16),256,0,stream>>>(in, dT, sT, CSM, h);
    } else {
      int total = (h>=4) ? 16*16*(h>>2) : 256;
      k_decompT<<<dim3((total+255)/256),256,0,stream>>>(in, dT, sT, CSM, h, total);
    }
  }

  // ---- phase 2: forward DFTs, batched ----
  k_fwdft_all<<<dim3(ftb.pcum[6],16,4),256,0,stream>>>(DTall, STall, TWF, FTPa, ftb);
  k_fwdeep_all<<<dim3(16,2,7),256,0,stream>>>(DTall, STall, FTPa, TWD, dpb);

  // ---- phase 3: reduce + mode mixing + YT transpose ----
  k_ftpred_all<<<dim3(512,13),256,0,stream>>>(FTPa, XAa, prb);
  k_modemix_lvl<<<dim3(64,8),256,0,stream>>>(XAa, WT, YTp, mxb);
  k_yttrans<<<dim3(16,2,13),256,0,stream>>>(YTp, YT2, mxb);

  // ---- phase 4: inverse DFTs, batched ----
  k_invdft_all<<<dim3(bxTot,16,2),256,0,stream>>>(YT2, TWI, UdAll, UsAll, ivb);
  k_invdeep_all<<<dim3(16,2,7),256,0,stream>>>(YT2, UdAll, UsAll, TWD, dpb);

  // ---- phase 5: LN+GELU and reconstruction chain ----
  k_lngelu<<<dim3(16),128,0,stream>>>(STall + lvl[12], CSM, XPA);
  bfu* rin = XPA;
  for(int i=12;i>=0;--i){
    int h = hv[i];
    void* rout = (i==0) ? d_out : (void*)((rin==XPA) ? XPB : XPA);
    int tot = 16*h*16;
    k_recon<<<dim3((tot+255)/256),256,0,stream>>>(rin, UsAll+lvl[i], UdAll+lvl[i], CSM, rout, h, 12-i, (i==0)?1:0, FLAG);
    rin = (bfu*)rout;
  }
}

// Round 9
// 497.846 us; speedup vs baseline: 1.3979x; 1.0108x over previous
//
#include <hip/hip_runtime.h>
#include <math.h>

typedef unsigned short bfu;   // raw bf16 bits
typedef short bf16x8 __attribute__((ext_vector_type(8)));
typedef float f32x4 __attribute__((ext_vector_type(4)));

__device__ __forceinline__ float bs2f(bfu s){
  union{ unsigned int u; float f; } v; v.u = ((unsigned int)s) << 16; return v.f;
}
__device__ __forceinline__ bfu f2bs(float f){
  union{ float ff; unsigned int u; } v; v.ff = f;
  unsigned int u = v.u;
  unsigned int r = (u + 0x7fffu + ((u >> 16) & 1u)) >> 16;   // RNE
  return (bfu)r;
}

struct LevelTab { int twoff[13]; int ll[13]; int logh[13]; };
struct WPtrs { const void* p[6]; };
struct FwTab { int pcum[7]; int h[6]; int np[6]; int twF[6]; long lvl[6]; long ftp[6]; };
struct DpTab { long lvl[7]; long ftp[7]; long yt[7]; int twD[7]; int h[7]; int l[7]; int lgh[7]; };
struct PrTab { int np[13]; int l[13]; long ftp[13]; long xa[13]; };
struct Mx2   { int lv[13]; int h[13]; long xa[13]; long yt[13]; };
struct IvTab { int bxcum[6]; int h[6]; int twF[6]; long yt[6]; long lvl[6]; };

// ---------------- dtype sniff ------------------------------------------------
__global__ __launch_bounds__(256) void k_sniff(const bfu* __restrict__ x, int* __restrict__ flag){
  __shared__ int cnt;
  if(threadIdx.x==0) cnt = 0;
  __syncthreads();
  int c = 0;
  for(int j=threadIdx.x; j<4096; j+=256){
    bfu v = x[2*j];
    int e = (v>>7)&0xFF;
    if(e >= 0xC0) c++;
  }
  atomicAdd(&cnt, c);
  __syncthreads();
  if(threadIdx.x==0) flag[0] = (cnt > 64) ? 1 : 0;
}

// ---------------- small arrays -> bf16 ---------------------------------------
__global__ __launch_bounds__(256) void k_cvt_small(
    const void* lnw, const void* lnb, const void* ecs, const void* ecd,
    const void* rce, const void* rco, bfu* __restrict__ CSM, const int* __restrict__ FLAG){
  int f32 = FLAG[0];
  const void* src[6] = {ecs, ecd, rce, rco, lnw, lnb};
  int tid = threadIdx.x;
  for(int a=0; a<6; ++a)
    for(int j=tid; j<128; j+=256)
      CSM[a*128+j] = f32 ? f2bs(((const float*)src[a])[j]) : ((const bfu*)src[a])[j];
}

// ---------------- weight transpose: W[i][o][f] -> W2[w][f][o][i], bf16 -------
__global__ __launch_bounds__(256) void k_wtrans(WPtrs wp, bfu* __restrict__ W2, const int* __restrict__ FLAG){
  int f32 = FLAG[0];
  int o = blockIdx.x;          // 0..127
  int w = blockIdx.y;          // 0..5
  __shared__ bfu tile[64][130];   // [f][i]
  int tid = threadIdx.x;
  const void* src = wp.p[w];
  if(f32){
    const float* s = (const float*)src;
    #pragma unroll
    for(int it=0; it<8; ++it){
      int e = it*256 + tid;
      int i = e >> 4, fq = e & 15;
      float4 v = *reinterpret_cast<const float4*>(s + ((size_t)i*128 + o)*64 + fq*4);
      tile[fq*4+0][i] = f2bs(v.x);
      tile[fq*4+1][i] = f2bs(v.y);
      tile[fq*4+2][i] = f2bs(v.z);
      tile[fq*4+3][i] = f2bs(v.w);
    }
  } else {
    const bfu* s = (const bfu*)src;
    #pragma unroll
    for(int it=0; it<4; ++it){
      int e = it*256 + tid;
      int i = e >> 3, fq = e & 7;
      union{uint4 u; bfu x[8];} U;
      U.u = *reinterpret_cast<const uint4*>(s + ((size_t)i*128 + o)*64 + fq*8);
      #pragma unroll
      for(int j=0;j<8;++j) tile[fq*8+j][i] = U.x[j];
    }
  }
  __syncthreads();
  bfu* dst = W2 + (size_t)w*64*128*128 + (size_t)o*128;
  #pragma unroll
  for(int it=0; it<8; ++it){
    int e = it*256 + tid;
    int f = e >> 5, iq = e & 31;
    union{uint2 u; bfu x[4];} P;
    #pragma unroll
    for(int j=0;j<4;++j) P.x[j] = tile[f][iq*4+j];
    *reinterpret_cast<uint2*>(dst + (size_t)f*128*128 + iq*4) = P.u;
  }
}

// ---------------- bf16 twiddle matrices for MFMA levels 0..5 -----------------
// hw v_sin/v_cos take REVOLUTIONS; m/h is already a revolution fraction.
__global__ __launch_bounds__(256) void k_twgenF(bfu* __restrict__ TWF, bfu* __restrict__ TWI){
  int e = blockIdx.x*256 + threadIdx.x;      // 0..1032191
  int kind = blockIdx.y;
  const int offs[7] = {0,524288,786432,917504,983040,1015808,1032192};
  int le = 5;
  #pragma unroll
  for(int i=0;i<6;++i){ if(e < offs[i+1]){ le = i; break; } }
  int rem = e - offs[le];
  int logh = 12 - le;
  int h = 1 << logh;
  int f, t, neg;
  if(kind==0){ int r = rem >> logh; t = rem & (h-1); f = (r<64)?r:(r-64); neg = (r>=64); }
  else       { t = rem >> 7; int f2 = rem & 127;     f = (f2<64)?f2:(f2-64); neg = (f2>=64); }
  int m = (f*t) & (h-1);
  float rev = (float)m / (float)h;
  float s = __builtin_amdgcn_sinf(rev);
  float c = __builtin_amdgcn_cosf(rev);
  float val = neg ? -s : c;
  if(kind==0) TWF[e] = f2bs(val); else TWI[e] = f2bs(val);
}

// ---------------- fp32 twiddles for deep levels ------------------------------
__global__ __launch_bounds__(256) void k_twgen(LevelTab lt, float* __restrict__ tw){
  int lev = blockIdx.y;
  int logh = lt.logh[lev];
  int h = 1 << logh;
  int l = lt.ll[lev];
  int tot = l*h;
  int idx = blockIdx.x*256 + threadIdx.x;
  if(idx >= tot) return;
  int t = idx & (h-1);
  int f = idx >> logh;
  int m = (f*t) & (h-1);
  float rev = (float)m / (float)h;
  tw[lt.twoff[lev] + idx] = __builtin_amdgcn_cosf(rev);
  tw[lt.twoff[lev] + tot + idx] = __builtin_amdgcn_sinf(rev);
}

// ---------------- level-0 decompose v3 ---------------------------------------
__global__ __launch_bounds__(256) void k_decomp0(
    const void* __restrict__ xin, bfu* __restrict__ dT, bfu* __restrict__ sT,
    const bfu* __restrict__ CSM, int h, const int* __restrict__ FLAG)
{
  int f32 = FLAG[0];
  __shared__ float ls[64][132];
  __shared__ bfu sdo[128][36];
  __shared__ bfu sso[128][36];
  __shared__ float Fd[16][8], Fs[16][8];
  int tid = threadIdx.x;
  if(tid < 128){ Fs[tid>>3][tid&7] = bs2f(CSM[tid]); Fd[tid>>3][tid&7] = bs2f(CSM[128+tid]); }
  int b = blockIdx.y;
  int t0in = blockIdx.x * 64;
  if(f32){
    const float* src = (const float*)xin + ((size_t)b*2*h + t0in)*128;
    #pragma unroll
    for(int it=0; it<8; ++it){
      int e = it*256 + tid;
      int row = e>>5, cq = e&31;
      float4 v = *reinterpret_cast<const float4*>(src + (size_t)row*128 + cq*4);
      ls[row][cq*4+0]=v.x; ls[row][cq*4+1]=v.y; ls[row][cq*4+2]=v.z; ls[row][cq*4+3]=v.w;
    }
  } else {
    const bfu* src = (const bfu*)xin + ((size_t)b*2*h + t0in)*128;
    #pragma unroll
    for(int it=0; it<4; ++it){
      int e = it*256 + tid;
      int row = e>>4, cq = e&15;
      union{uint4 u; bfu x[8];} U;
      U.u = *reinterpret_cast<const uint4*>(src + (size_t)row*128 + cq*8);
      #pragma unroll
      for(int j=0;j<8;++j) ls[row][cq*8+j] = bs2f(U.x[j]);
    }
  }
  __syncthreads();
  int g = tid>>7, ch = tid&127;
  int c = ch>>3, kp = ch&7;
  float fdE[8], fdO[8], fsE[8], fsO[8];
  #pragma unroll
  for(int j=0;j<8;++j){ fdE[j]=Fd[j][kp]; fdO[j]=Fd[8+j][kp]; fsE[j]=Fs[j][kp]; fsO[j]=Fs[8+j][kp]; }
  union{ uint2 u; bfu x[4]; } Dq, Sq;
  #pragma unroll
  for(int tl=0; tl<16; ++tl){
    int rl = 2*(g*16+tl);
    const float* ev = &ls[rl][c*8];
    const float* od = &ls[rl+1][c*8];
    float d=0.f, s=0.f;
    #pragma unroll
    for(int j=0;j<8;++j){
      d += ev[j]*fdE[j] + od[j]*fdO[j];
      s += ev[j]*fsE[j] + od[j]*fsO[j];
    }
    Dq.x[tl&3] = f2bs(d); Sq.x[tl&3] = f2bs(s);
    if((tl&3)==3){
      int tb = g*16 + (tl & ~3);
      *reinterpret_cast<uint2*>(&sdo[ch][tb]) = Dq.u;
      *reinterpret_cast<uint2*>(&sso[ch][tb]) = Sq.u;
    }
  }
  __syncthreads();
  size_t obase = (size_t)b*128*h + (t0in>>1);
  #pragma unroll
  for(int it=0; it<4; ++it){
    int e = it*256 + tid;
    int r = e >> 3, kq = e & 7;
    union{uint2 u; bfu x[4];} P;
    #pragma unroll
    for(int j=0;j<4;++j) P.x[j] = sdo[r][kq*4+j];
    *reinterpret_cast<uint2*>(dT + obase + (size_t)r*h + kq*4) = P.u;
  }
  #pragma unroll
  for(int it=0; it<4; ++it){
    int e = it*256 + tid;
    int r = e >> 3, kq = e & 7;
    union{uint2 u; bfu x[4];} P;
    #pragma unroll
    for(int j=0;j<4;++j) P.x[j] = sso[r][kq*4+j];
    *reinterpret_cast<uint2*>(sT + obase + (size_t)r*h + kq*4) = P.u;
  }
}

// ---------------- transposed decompose, big levels (h >= 256) ----------------
__global__ __launch_bounds__(256) void k_decompT_big(
    const bfu* __restrict__ inT, bfu* __restrict__ dT, bfu* __restrict__ sT,
    const bfu* __restrict__ CSM, int h)
{
  __shared__ float Fd[16][8], Fs[16][8];
  int tid = threadIdx.x;
  if(tid < 128){ Fs[tid>>3][tid&7] = bs2f(CSM[tid]); Fd[tid>>3][tid&7] = bs2f(CSM[128+tid]); }
  __syncthreads();
  int tt0 = blockIdx.x * 256;
  int b = blockIdx.y, c = blockIdx.z;
  int kp = tid >> 5, tq = tid & 31;
  float fdE[8], fdO[8], fsE[8], fsO[8];
  #pragma unroll
  for(int k=0;k<8;++k){ fdE[k]=Fd[k][kp]; fdO[k]=Fd[8+k][kp]; fsE[k]=Fs[k][kp]; fsO[k]=Fs[8+k][kp]; }
  const bfu* base = inT + ((size_t)b*128 + c*8)*(size_t)(2*h) + (size_t)2*tt0 + tq*16;
  union{uint4 u[2]; bfu x[16];} E[8];
  #pragma unroll
  for(int k=0;k<8;++k){
    E[k].u[0] = *reinterpret_cast<const uint4*>(base + (size_t)k*(2*h));
    E[k].u[1] = *reinterpret_cast<const uint4*>(base + (size_t)k*(2*h) + 8);
  }
  union{uint4 u; bfu x[8];} Od, Os;
  #pragma unroll
  for(int to=0; to<8; ++to){
    float d=0.f, s=0.f;
    #pragma unroll
    for(int k=0;k<8;++k){
      float ev = bs2f(E[k].x[2*to]), od = bs2f(E[k].x[2*to+1]);
      d += ev*fdE[k] + od*fdO[k];
      s += ev*fsE[k] + od*fsO[k];
    }
    Od.x[to] = f2bs(d); Os.x[to] = f2bs(s);
  }
  size_t ob = ((size_t)b*128 + c*8 + kp)*h + tt0 + tq*8;
  *reinterpret_cast<uint4*>(dT + ob) = Od.u;
  *reinterpret_cast<uint4*>(sT + ob) = Os.u;
}

// ---------------- transposed decompose (small levels) ------------------------
__global__ __launch_bounds__(256) void k_decompT(
    const bfu* __restrict__ inT, bfu* __restrict__ dT, bfu* __restrict__ sT,
    const bfu* __restrict__ CSM, int h, int total)
{
  __shared__ float Fd[16][8], Fs[16][8];
  int tid = threadIdx.x;
  if(tid < 128){ Fs[tid>>3][tid&7] = bs2f(CSM[tid]); Fd[tid>>3][tid&7] = bs2f(CSM[128+tid]); }
  __syncthreads();
  int idx = blockIdx.x*256 + tid;
  if(idx >= total) return;
  if(h >= 4){
    int nto = h>>2;
    int to = idx & (nto-1);
    int bc = idx / nto;
    int c = bc & 15, b = bc >> 4;
    const bfu* base = inT + ((size_t)b*128 + c*8)*(size_t)(2*h) + to*8;
    float d8[4][8] = {}, s8[4][8] = {};
    #pragma unroll
    for(int k=0;k<8;++k){
      union{uint4 u; bfu x[8];} U;
      U.u = *reinterpret_cast<const uint4*>(base + (size_t)k*(2*h));
      const float* fdE = Fd[k]; const float* fdO = Fd[8+k];
      const float* fsE = Fs[k]; const float* fsO = Fs[8+k];
      #pragma unroll
      for(int tl=0; tl<4; ++tl){
        float ev = bs2f(U.x[2*tl]), od = bs2f(U.x[2*tl+1]);
        #pragma unroll
        for(int kp=0;kp<8;++kp){
          d8[tl][kp] += ev*fdE[kp] + od*fdO[kp];
          s8[tl][kp] += ev*fsE[kp] + od*fsO[kp];
        }
      }
    }
    #pragma unroll
    for(int kp=0;kp<8;++kp){
      union{uint2 u; bfu x[4];} Od, Os;
      #pragma unroll
      for(int tl=0;tl<4;++tl){ Od.x[tl]=f2bs(d8[tl][kp]); Os.x[tl]=f2bs(s8[tl][kp]); }
      size_t ob = ((size_t)b*128 + c*8 + kp)*h + to*4;
      *reinterpret_cast<uint2*>(dT + ob) = Od.u;
      *reinterpret_cast<uint2*>(sT + ob) = Os.u;
    }
  } else {
    int c = idx & 15, b = idx >> 4;
    const bfu* base = inT + ((size_t)b*128 + c*8)*(size_t)(2*h);
    for(int tl=0; tl<h; ++tl){
      float d8[8]={}, s8[8]={};
      for(int k=0;k<8;++k){
        float ev = bs2f(base[(size_t)k*2*h + 2*tl]);
        float od = bs2f(base[(size_t)k*2*h + 2*tl+1]);
        #pragma unroll
        for(int kp=0;kp<8;++kp){
          d8[kp] += ev*Fd[k][kp] + od*Fd[8+k][kp];
          s8[kp] += ev*Fs[k][kp] + od*Fs[8+k][kp];
        }
      }
      for(int kp=0;kp<8;++kp){
        size_t ob = ((size_t)b*128 + c*8 + kp)*h + tl;
        dT[ob] = f2bs(d8[kp]); sT[ob] = f2bs(s8[kp]);
      }
    }
  }
}

// ---------------- MFMA forward DFT, batched levels 0..5 ----------------------
// np = h/512 -> Kpart <= 512 (<= 8 K-chunks per block), grid (17,16,4).
__global__ __launch_bounds__(256) void k_fwdft_all(
    const bfu* __restrict__ DTall, const bfu* __restrict__ STall,
    const bfu* __restrict__ TWF, float* __restrict__ FTPa, FwTab ft)
{
  int gp = blockIdx.x, b = blockIdx.y;
  int sig = blockIdx.z >> 1, rh = blockIdx.z & 1;
  int lev = 0;
  for(int i=5;i>0;--i){ if(gp >= ft.pcum[i]){ lev = i; break; } }
  int p = gp - ft.pcum[lev];
  int h = ft.h[lev];
  int Kpart = h / ft.np[lev];
  const bfu* SIG = (sig ? STall : DTall) + ft.lvl[lev] + (size_t)b*128*h;
  const bfu* TWr = TWF + ft.twF[lev] + (size_t)(rh*64)*h;
  __shared__ bfu lsA[64*72];
  __shared__ bfu lsB[128*72];
  int tid = threadIdx.x;
  int wave = tid>>6, lane = tid&63;
  int mh = (wave>>1)*32, nh = (wave&1)*64;
  int ml = lane&15, q = lane>>4;
  f32x4 acc[2][4];
  #pragma unroll
  for(int i=0;i<2;++i){
    #pragma unroll
    for(int j=0;j<4;++j) acc[i][j] = (f32x4)0.f;
  }
  int k0base = p*Kpart;
  for(int kc=0; kc<Kpart; kc+=64){
    int k0 = k0base + kc;
    #pragma unroll
    for(int it=0; it<2; ++it){
      int slot = it*256 + tid;
      int row = slot>>3, kq = slot&7;
      *reinterpret_cast<uint4*>(&lsA[row*72 + kq*8]) =
        *reinterpret_cast<const uint4*>(&TWr[(size_t)row*h + k0 + kq*8]);
    }
    #pragma unroll
    for(int it=0; it<4; ++it){
      int slot = it*256 + tid;
      int row = slot>>3, kq = slot&7;
      *reinterpret_cast<uint4*>(&lsB[row*72 + kq*8]) =
        *reinterpret_cast<const uint4*>(&SIG[(size_t)row*h + k0 + kq*8]);
    }
    __syncthreads();
    #pragma unroll
    for(int kk=0; kk<64; kk+=32){
      bf16x8 af[2], bfr[4];
      #pragma unroll
      for(int mi=0;mi<2;++mi)
        af[mi] = *reinterpret_cast<const bf16x8*>(&lsA[(mh+mi*16+ml)*72 + kk + q*8]);
      #pragma unroll
      for(int ni=0;ni<4;++ni)
        bfr[ni] = *reinterpret_cast<const bf16x8*>(&lsB[(nh+ni*16+ml)*72 + kk + q*8]);
      #pragma unroll
      for(int mi=0;mi<2;++mi){
        #pragma unroll
        for(int ni=0;ni<4;++ni)
          acc[mi][ni] = __builtin_amdgcn_mfma_f32_16x16x32_bf16(af[mi], bfr[ni], acc[mi][ni], 0,0,0);
      }
    }
    __syncthreads();
  }
  float* dst = FTPa + ft.ftp[lev] + (((size_t)p*2 + sig)*16 + b)*16384;
  #pragma unroll
  for(int mi=0;mi<2;++mi){
    #pragma unroll
    for(int ni=0;ni<4;++ni){
      int row = rh*64 + mh + mi*16 + q*4;
      int col = nh + ni*16 + ml;
      #pragma unroll
      for(int r=0;r<4;++r)
        dst[(size_t)(row+r)*128 + col] = acc[mi][ni][r];
    }
  }
}

// ---------------- deep forward DFT, batched levels 6..12 ---------------------
__global__ __launch_bounds__(256) void k_fwdeep_all(
    const bfu* __restrict__ DTall, const bfu* __restrict__ STall,
    float* __restrict__ FTPa, const float* __restrict__ TWD, DpTab dp)
{
  int b = blockIdx.x, sig = blockIdx.y, j = blockIdx.z;
  int h = dp.h[j], l = dp.l[j], logh = dp.lgh[j];
  const bfu* src = (sig? STall : DTall) + dp.lvl[j] + (size_t)b*128*h;
  float* dst = FTPa + dp.ftp[j] + ((size_t)sig*16 + b)*16384;
  const float* TWc = TWD + dp.twD[j];
  __shared__ float s_sig[128*65];
  __shared__ float s_twc[33*64];
  __shared__ float s_tws[33*64];
  int tid = threadIdx.x;
  int hp = h + 1;
  for(int e = tid; e < 128*h; e += 256){
    int ch = e >> logh, t = e & (h-1);
    s_sig[ch*hp + t] = bs2f(src[e]);
  }
  int lh = l*h;
  const float* TWs = TWc + (size_t)lh;
  for(int e = tid; e < lh; e += 256){ s_twc[e] = TWc[e]; s_tws[e] = TWs[e]; }
  __syncthreads();
  for(int idx = tid; idx < l*128; idx += 256){
    int f = idx >> 7, ch = idx & 127;
    const float* sp = &s_sig[ch*hp];
    const float* cp = &s_twc[f*h];
    const float* zp = &s_tws[f*h];
    float re = 0.f, im = 0.f;
    for(int t=0; t<h; ++t){ float v = sp[t]; re += v*cp[t]; im -= v*zp[t]; }
    dst[(size_t)f*128 + ch] = re;
    dst[(size_t)(64+f)*128 + ch] = im;
  }
}

// ---------------- FTP reduce + A-matrix build, batched all levels ------------
__global__ __launch_bounds__(256) void k_ftpred_all(
    const float* __restrict__ FTPa, bfu* __restrict__ XAa, PrTab pt)
{
  int lev = blockIdx.y;
  int e = blockIdx.x*256 + threadIdx.x;     // 0..131071
  const size_t PS = (size_t)2*16*128*128;
  int ch4 = e & 31;
  int row = (e>>5) & 127;
  int b   = (e>>12) & 15;
  int sig = e>>16;
  int f = row & 63, im = row >> 6;
  if(f >= pt.l[lev]) return;
  const float* F = FTPa + pt.ftp[lev];
  int np = pt.np[lev];
  size_t src = (((size_t)sig*16 + b)*128 + row)*128 + (size_t)ch4*4;
  f32x4 v = *reinterpret_cast<const f32x4*>(&F[src]);
  for(int p=1;p<np;++p)
    v += *reinterpret_cast<const f32x4*>(&F[src + (size_t)p*PS]);
  int ch = ch4*4;
  union{ uint2 u; bfu x[4]; } P1, P3;
  #pragma unroll
  for(int j=0;j<4;++j){
    float vj = v[j];
    P1.x[j] = f2bs(im ? -vj : vj);
    P3.x[j] = f2bs(vj);
  }
  bfu* XA = XAa + pt.xa[lev];
  size_t base = (size_t)f*32*512;
  *reinterpret_cast<uint2*>(&XA[base + (size_t)b*512 + sig*256 + im*128 + ch]) = P1.u;
  *reinterpret_cast<uint2*>(&XA[base + (size_t)(16+b)*512 + sig*256 + (1-im)*128 + ch]) = P3.u;
}

// ---------------- MFMA mode mixing: level-loop, reg-hoisted weights ----------
__global__ __launch_bounds__(256) void k_modemix_lvl(
    const bfu* __restrict__ XAa, const bfu* __restrict__ W2,
    bfu* __restrict__ YTp, Mx2 mt)
{
  int f = blockIdx.x;
  int obase = blockIdx.y * 16;
  int tid = threadIdx.x;
  int wid = tid>>6, lane = tid&63;
  int m = wid & 1, part = wid >> 1;
  int ml = lane & 15, q = lane >> 4;
  const size_t WSZ = (size_t)64*128*128;
  const bfu* Wb = W2 + ((size_t)f*128 + obase + ml)*128 + q*8;
  bf16x8 wf[16];
  if(part == 0){
    #pragma unroll
    for(int ks=0; ks<16; ++ks)
      wf[ks] = *reinterpret_cast<const bf16x8*>(Wb + (size_t)(ks>>2)*WSZ + (ks&3)*32);
  } else {
    #pragma unroll
    for(int ks=0; ks<8; ++ks)
      wf[ks] = *reinterpret_cast<const bf16x8*>(Wb + (size_t)(4 + (ks>>2))*WSZ + (ks&3)*32);
  }
  __shared__ bfu lsA[32*520];      // stride 520 -> 2-way banks, 16B aligned
  for(int lev=0; lev<13; ++lev){
    if(f >= mt.lv[lev]) continue;
    const bfu* Asrc = XAa + mt.xa[lev] + (size_t)f*16384;
    #pragma unroll
    for(int it=0; it<8; ++it){
      int slot = it*256 + tid;       // 2048 uint4 = 32 rows x 64 kq
      int row = slot>>6, kq = slot&63;
      *reinterpret_cast<uint4*>(&lsA[row*520 + kq*8]) =
        *reinterpret_cast<const uint4*>(&Asrc[(size_t)row*512 + kq*8]);
    }
    __syncthreads();
    const bfu* Ar = &lsA[(m*16+ml)*520 + q*8];
    f32x4 acc = (f32x4)0.f;
    if(part == 0){
      #pragma unroll
      for(int ks=0; ks<16; ++ks){
        bf16x8 A = *reinterpret_cast<const bf16x8*>(Ar + ks*32);
        acc = __builtin_amdgcn_mfma_f32_16x16x32_bf16(A, wf[ks], acc, 0,0,0);
      }
    } else {
      #pragma unroll
      for(int ks=0; ks<8; ++ks){
        bf16x8 A = *reinterpret_cast<const bf16x8*>(Ar + ks*32);
        acc = __builtin_amdgcn_mfma_f32_16x16x32_bf16(A, wf[ks], acc, 0,0,0);
      }
    }
    int h = mt.h[lev];
    bool edge = (f==0) || (2*f == h);
    float sc = edge ? 1.0f/(float)h : 2.0f/(float)h;
    int fo = m ? (64+f) : f;
    bfu* dst = YTp + mt.yt[lev] + (part ? (size_t)16*128*128 : 0);
    #pragma unroll
    for(int r=0;r<4;++r){
      int b = q*4 + r;
      float val = acc[r]*sc;
      if(m && edge) val = 0.f;
      dst[((size_t)b*128 + fo)*128 + obase + ml] = f2bs(val);
    }
    __syncthreads();
  }
}

// ---------------- YT transpose: Y'[u][b][fo][ch] -> Y[u][b][ch][fo] ----------
__global__ __launch_bounds__(256) void k_yttrans(
    const bfu* __restrict__ YTp, bfu* __restrict__ YT2, Mx2 mt)
{
  int b = blockIdx.x, u = blockIdx.y, lev = blockIdx.z;
  const bfu* src = YTp + mt.yt[lev] + ((size_t)u*16 + b)*16384;
  bfu* dst = YT2 + mt.yt[lev] + ((size_t)u*16 + b)*16384;
  __shared__ bfu tile[128][130];
  int tid = threadIdx.x;
  #pragma unroll
  for(int it=0; it<8; ++it){
    int slot = it*256 + tid;        // 2048 uint4 = 128 fo x 16 kq
    int fo = slot>>4, kq = slot&15;
    union{uint4 u4; bfu x[8];} U;
    U.u4 = *reinterpret_cast<const uint4*>(&src[(size_t)fo*128 + kq*8]);
    #pragma unroll
    for(int j=0;j<8;++j) tile[kq*8+j][fo] = U.x[j];
  }
  __syncthreads();
  #pragma unroll
  for(int it=0; it<8; ++it){
    int slot = it*256 + tid;        // 2048 uint4 = 128 ch x 16 kq
    int ch = slot>>4, kq = slot&15;
    union{uint4 u4; bfu x[8];} P;
    #pragma unroll
    for(int j=0;j<8;++j) P.x[j] = tile[ch][kq*8+j];
    *reinterpret_cast<uint4*>(&dst[(size_t)ch*128 + kq*8]) = P.u4;
  }
}

// ---------------- MFMA inverse DFT, batched levels 0..5 ----------------------
__global__ __launch_bounds__(256) void k_invdft_all(
    const bfu* __restrict__ YTa, const bfu* __restrict__ TWI,
    bfu* __restrict__ UdAll, bfu* __restrict__ UsAll, IvTab iv)
{
  int x = blockIdx.x, b = blockIdx.y, u = blockIdx.z;
  int lev = 0;
  for(int i=5;i>0;--i){ if(x >= iv.bxcum[i]){ lev = i; break; } }
  int bx = x - iv.bxcum[lev];
  int h = iv.h[lev];
  bfu* outp = (u ? UsAll : UdAll) + iv.lvl[lev];
  const bfu* Y = YTa + iv.yt[lev] + ((size_t)u*16 + b)*16384;
  const bfu* TWIl = TWI + iv.twF[lev];
  int t0 = bx*128;
  __shared__ bfu lsA[128*136];
  __shared__ bfu lsB[128*136];
  int tid = threadIdx.x;
  #pragma unroll
  for(int it=0; it<8; ++it){
    int slot = it*256 + tid;
    int row = slot>>4, kq = slot&15;
    *reinterpret_cast<uint4*>(&lsA[row*136 + kq*8]) =
      *reinterpret_cast<const uint4*>(&TWIl[(size_t)(t0+row)*128 + kq*8]);
    *reinterpret_cast<uint4*>(&lsB[row*136 + kq*8]) =
      *reinterpret_cast<const uint4*>(&Y[(size_t)row*128 + kq*8]);
  }
  __syncthreads();
  int wave = tid>>6, lane = tid&63;
  int mh = (wave>>1)*64, nh = (wave&1)*64;
  int ml = lane&15, q = lane>>4;
  f32x4 acc[4][4];
  #pragma unroll
  for(int i=0;i<4;++i){
    #pragma unroll
    for(int j=0;j<4;++j) acc[i][j] = (f32x4)0.f;
  }
  #pragma unroll
  for(int kk=0; kk<128; kk+=32){
    bf16x8 af[4], bfr[4];
    #pragma unroll
    for(int mi=0;mi<4;++mi)
      af[mi] = *reinterpret_cast<const bf16x8*>(&lsA[(mh+mi*16+ml)*136 + kk + q*8]);
    #pragma unroll
    for(int ni=0;ni<4;++ni)
      bfr[ni] = *reinterpret_cast<const bf16x8*>(&lsB[(nh+ni*16+ml)*136 + kk + q*8]);
    #pragma unroll
    for(int mi=0;mi<4;++mi){
      #pragma unroll
      for(int ni=0;ni<4;++ni)
        acc[mi][ni] = __builtin_amdgcn_mfma_f32_16x16x32_bf16(af[mi], bfr[ni], acc[mi][ni], 0,0,0);
    }
  }
  #pragma unroll
  for(int mi=0;mi<4;++mi){
    #pragma unroll
    for(int ni=0;ni<4;++ni){
      int row = mh + mi*16 + q*4;
      int col = nh + ni*16 + ml;
      #pragma unroll
      for(int r=0;r<4;++r)
        outp[((size_t)b*h + t0+row+r)*128 + col] = f2bs(acc[mi][ni][r]);
    }
  }
}

// ---------------- deep inverse DFT, batched levels 6..12 ---------------------
__global__ __launch_bounds__(256) void k_invdeep_all(
    const bfu* __restrict__ YTa, bfu* __restrict__ UdAll, bfu* __restrict__ UsAll,
    const float* __restrict__ TWD, DpTab dp)
{
  int b = blockIdx.x, u = blockIdx.y, j = blockIdx.z;
  int h = dp.h[j], l = dp.l[j];
  bfu* outp = (u? UsAll : UdAll) + dp.lvl[j] + (size_t)b*h*128;
  const bfu* Y = YTa + dp.yt[j] + ((size_t)u*16 + b)*16384;
  const float* TWc = TWD + dp.twD[j];
  __shared__ float s_yr[128*66];
  __shared__ float s_yi[128*66];
  __shared__ float s_twc[33*64];
  __shared__ float s_tws[33*64];
  int tid = threadIdx.x;
  #pragma unroll
  for(int it=0; it<8; ++it){
    int slot = it*256 + tid;
    int ch = slot >> 4, kq = slot & 15;
    union{uint4 u4; bfu x[8];} U;
    U.u4 = *reinterpret_cast<const uint4*>(&Y[(size_t)ch*128 + kq*8]);
    if(kq < 8){
      #pragma unroll
      for(int jj=0;jj<8;++jj) s_yr[ch*66 + kq*8 + jj] = bs2f(U.x[jj]);
    } else {
      #pragma unroll
      for(int jj=0;jj<8;++jj) s_yi[ch*66 + (kq-8)*8 + jj] = bs2f(U.x[jj]);
    }
  }
  int lh = l*h;
  const float* TWs = TWc + (size_t)lh;
  for(int e = tid; e < lh; e += 256){ s_twc[e] = TWc[e]; s_tws[e] = TWs[e]; }
  __syncthreads();
  for(int idx = tid; idx < h*128; idx += 256){
    int t = idx >> 7, ch = idx & 127;
    const float* yr = &s_yr[ch*66];
    const float* yi = &s_yi[ch*66];
    float a = 0.f;
    for(int f=0; f<l; ++f)
      a += yr[f]*s_twc[f*h + t] - yi[f]*s_tws[f*h + t];
    outp[idx] = f2bs(a);
  }
}

// ---------------- LayerNorm + exact GELU on (16,1,128) -----------------------
__global__ __launch_bounds__(128) void k_lngelu(
    const bfu* __restrict__ xin, const bfu* __restrict__ CSM, bfu* __restrict__ xout)
{
  int b = blockIdx.x, tid = threadIdx.x;
  float v = bs2f(xin[b*128 + tid]);
  float s1 = v, s2 = v*v;
  #pragma unroll
  for(int o=32; o; o>>=1){ s1 += __shfl_down(s1,o); s2 += __shfl_down(s2,o); }
  __shared__ float red[2][2];
  int w = tid >> 6;
  if((tid & 63) == 0){ red[w][0]=s1; red[w][1]=s2; }
  __syncthreads();
  float m  = (red[0][0]+red[1][0]) * (1.0f/128.0f);
  float ms = (red[0][1]+red[1][1]) * (1.0f/128.0f);
  float var = ms - m*m;
  float xn = (v - m) * rsqrtf(var + 1e-5f) * bs2f(CSM[512+tid]) + bs2f(CSM[640+tid]);
  float g = 0.5f * xn * (1.0f + erff(xn * 0.70710678118654752f));
  xout[b*128 + tid] = f2bs(g);
}

// ---------------- reconstruction step ([t][ch] layout) -----------------------
__global__ __launch_bounds__(256) void k_recon(
    const bfu* __restrict__ xin, const bfu* __restrict__ usp, const bfu* __restrict__ udp,
    const bfu* __restrict__ CSM, void* __restrict__ xout, int h, int logh,
    int is_final, const int* __restrict__ FLAG)
{
  int f32 = is_final ? FLAG[0] : 0;
  __shared__ float Fe[16][8], Fo[16][8];
  int tid = threadIdx.x;
  if(tid < 128){ Fe[tid>>3][tid&7] = bs2f(CSM[256+tid]); Fo[tid>>3][tid&7] = bs2f(CSM[384+tid]); }
  __syncthreads();
  int idx = blockIdx.x*256 + tid;
  if(idx >= 16*h*16) return;
  int c  = idx & 15;
  int bt = idx >> 4;
  int t  = bt & (h-1);
  int b  = bt >> logh;
  size_t base = (((size_t)bt) << 7) + (c<<3);
  union{ uint4 u; bfu x[8]; } X, U, D;
  X.u = *reinterpret_cast<const uint4*>(xin + base);
  U.u = *reinterpret_cast<const uint4*>(usp + base);
  D.u = *reinterpret_cast<const uint4*>(udp + base);
  float y[16];
  #pragma unroll
  for(int j=0;j<8;++j){ y[j] = bs2f(X.x[j]) + bs2f(U.x[j]); y[8+j] = bs2f(D.x[j]); }
  float e8[8] = {0,0,0,0,0,0,0,0}, o8[8] = {0,0,0,0,0,0,0,0};
  #pragma unroll
  for(int j=0;j<16;++j){
    float v = y[j];
    #pragma unroll
    for(int k=0;k<8;++k){ e8[k] += v*Fe[j][k]; o8[k] += v*Fo[j][k]; }
  }
  size_t ob = (((size_t)(b*(h<<1) + (t<<1))) << 7) + (c<<3);
  if(f32){
    float* po = (float*)xout;
    *reinterpret_cast<float4*>(po + ob)       = make_float4(e8[0],e8[1],e8[2],e8[3]);
    *reinterpret_cast<float4*>(po + ob + 4)   = make_float4(e8[4],e8[5],e8[6],e8[7]);
    *reinterpret_cast<float4*>(po + ob + 128) = make_float4(o8[0],o8[1],o8[2],o8[3]);
    *reinterpret_cast<float4*>(po + ob + 132) = make_float4(o8[4],o8[5],o8[6],o8[7]);
  } else {
    union{ uint4 u; bfu x[8]; } Oe, Oo;
    #pragma unroll
    for(int k=0;k<8;++k){ Oe.x[k] = f2bs(e8[k]); Oo.x[k] = f2bs(o8[k]); }
    bfu* po = (bfu*)xout;
    *reinterpret_cast<uint4*>(po + ob)       = Oe.u;
    *reinterpret_cast<uint4*>(po + ob + 128) = Oo.u;
  }
}

// ============================================================================
extern "C" void kernel_launch(void* const* d_in, const int* in_sizes, int n_in,
                              void* d_out, int out_size, void* d_ws, size_t ws_size,
                              hipStream_t stream)
{
  (void)in_sizes; (void)n_in; (void)out_size; (void)ws_size;
  const void* x0 = d_in[0];
  WPtrs wp;
  for(int w=0;w<6;++w) wp.p[w] = d_in[1+w];

  char* ws = (char*)d_ws;
  size_t off = 0;
  auto carve = [&](size_t bytes)->char*{
    char* p = ws + off; off += (bytes + 255) & ~(size_t)255; return p; };

  // level params
  int hv[13], lv[13], npv[13];
  const int offF[6] = {0,524288,786432,917504,983040,1015808};
  for(int i=0;i<13;++i){
    hv[i] = 4096 >> i;
    int l = hv[i]/2 + 1;
    lv[i] = (l < 64) ? l : 64;
    npv[i] = (i < 6) ? ((hv[i]/512 > 0) ? hv[i]/512 : 1) : 1;   // 8,4,2,1,1,1,...
  }
  long lvl[13]; long aTot = 0;
  for(int i=0;i<13;++i){ lvl[i] = aTot; aTot += (long)16*128*hv[i]; }
  long ftpo[13]; long fsl = 0;
  for(int i=0;i<13;++i){ ftpo[i] = fsl*524288L; fsl += npv[i]; }
  long xao[13]; long xsl = 0;
  for(int i=0;i<13;++i){ xao[i] = xsl; xsl += (long)lv[i]*16384; }
  long yto[13];
  for(int i=0;i<13;++i) yto[i] = (long)i*524288;

  int* FLAG = (int*)carve(256);
  bfu* CSM  = (bfu*)carve(2048);
  bfu* STall = (bfu*)carve((size_t)aTot*2);
  bfu* DTall = (bfu*)carve((size_t)aTot*2);
  bfu* UdAll = (bfu*)carve((size_t)aTot*2);
  bfu* UsAll = (bfu*)carve((size_t)aTot*2);
  bfu* WT   = (bfu*)carve((size_t)6*64*128*128*2);
  bfu* XAa  = (bfu*)carve((size_t)xsl*2);
  bfu* YTp  = (bfu*)carve((size_t)13*524288*2);    // Y'[u][b][fo][ch]
  bfu* YT2  = (bfu*)carve((size_t)13*524288*2);    // Y[u][b][ch][fo]
  bfu* TWF  = (bfu*)carve((size_t)1032192*2);
  bfu* TWI  = (bfu*)carve((size_t)1032192*2);
  float* FTPa = (float*)carve((size_t)fsl*524288*4);

  // deep fp32 twiddles (levels 6..12)
  LevelTab lt;
  int acc = 0;
  for(int j=0;j<7;++j){
    int i = 6+j;
    lt.twoff[j]=acc; lt.ll[j]=lv[i]; lt.logh[j]=12-i;
    acc += 2*lv[i]*hv[i];
  }
  for(int j=7;j<13;++j){ lt.twoff[j]=0; lt.ll[j]=1; lt.logh[j]=0; }
  float* TWD = (float*)carve((size_t)acc*4);

  bfu* XPA = DTall;            // recon ping-pong (reuse, post-spectral)
  bfu* XPB = (bfu*)FTPa;

  // batch tables
  FwTab ftb; { int pc=0;
    for(int i=0;i<6;++i){ ftb.pcum[i]=pc; pc+=npv[i]; ftb.h[i]=hv[i]; ftb.np[i]=npv[i];
                          ftb.twF[i]=offF[i]; ftb.lvl[i]=lvl[i]; ftb.ftp[i]=ftpo[i]; }
    ftb.pcum[6]=pc; }
  DpTab dpb;
  for(int j=0;j<7;++j){ int i=6+j;
    dpb.lvl[j]=lvl[i]; dpb.ftp[j]=ftpo[i]; dpb.yt[j]=yto[i]; dpb.twD[j]=lt.twoff[j];
    dpb.h[j]=hv[i]; dpb.l[j]=lv[i]; dpb.lgh[j]=12-i; }
  PrTab prb;
  for(int i=0;i<13;++i){ prb.np[i]=npv[i]; prb.l[i]=lv[i]; prb.ftp[i]=ftpo[i]; prb.xa[i]=xao[i]; }
  Mx2 mxb;
  for(int i=0;i<13;++i){ mxb.lv[i]=lv[i]; mxb.h[i]=hv[i]; mxb.xa[i]=xao[i]; mxb.yt[i]=yto[i]; }
  IvTab ivb; int bxTot=0;
  for(int i=0;i<6;++i){ ivb.bxcum[i]=bxTot; bxTot+=hv[i]/128; ivb.h[i]=hv[i];
                        ivb.twF[i]=offF[i]; ivb.yt[i]=yto[i]; ivb.lvl[i]=lvl[i]; }

  // ---- setup ----
  k_sniff<<<dim3(1),256,0,stream>>>((const bfu*)x0, FLAG);
  k_cvt_small<<<dim3(1),256,0,stream>>>(d_in[7], d_in[8], d_in[9], d_in[10], d_in[11], d_in[12], CSM, FLAG);
  k_wtrans<<<dim3(128,6),256,0,stream>>>(wp, WT, FLAG);
  k_twgenF<<<dim3(4032,2),256,0,stream>>>(TWF, TWI);
  k_twgen<<<dim3(17,7),256,0,stream>>>(lt, TWD);

  // ---- phase 1: decompose chain (sequential) ----
  k_decomp0<<<dim3(hv[0]/32,16),256,0,stream>>>(x0, DTall+lvl[0], STall+lvl[0], CSM, hv[0], FLAG);
  for(int i=1;i<13;++i){
    int h = hv[i];
    const bfu* in = STall + lvl[i-1];
    bfu* dT = DTall + lvl[i];
    bfu* sT = STall + lvl[i];
    if(h >= 256){
      k_decompT_big<<<dim3(h/256,16,16),256,0,stream>>>(in, dT, sT, CSM, h);
    } else {
      int total = (h>=4) ? 16*16*(h>>2) : 256;
      k_decompT<<<dim3((total+255)/256),256,0,stream>>>(in, dT, sT, CSM, h, total);
    }
  }

  // ---- phase 2: forward DFTs, batched ----
  k_fwdft_all<<<dim3(ftb.pcum[6],16,4),256,0,stream>>>(DTall, STall, TWF, FTPa, ftb);
  k_fwdeep_all<<<dim3(16,2,7),256,0,stream>>>(DTall, STall, FTPa, TWD, dpb);

  // ---- phase 3: reduce + mode mixing + YT transpose ----
  k_ftpred_all<<<dim3(512,13),256,0,stream>>>(FTPa, XAa, prb);
  k_modemix_lvl<<<dim3(64,8),256,0,stream>>>(XAa, WT, YTp, mxb);
  k_yttrans<<<dim3(16,2,13),256,0,stream>>>(YTp, YT2, mxb);

  // ---- phase 4: inverse DFTs, batched ----
  k_invdft_all<<<dim3(bxTot,16,2),256,0,stream>>>(YT2, TWI, UdAll, UsAll, ivb);
  k_invdeep_all<<<dim3(16,2,7),256,0,stream>>>(YT2, UdAll, UsAll, TWD, dpb);

  // ---- phase 5: LN+GELU and reconstruction chain ----
  k_lngelu<<<dim3(16),128,0,stream>>>(STall + lvl[12], CSM, XPA);
  bfu* rin = XPA;
  for(int i=12;i>=0;--i){
    int h = hv[i];
    void* rout = (i==0) ? d_out : (void*)((rin==XPA) ? XPB : XPA);
    int tot = 16*h*16;
    k_recon<<<dim3((tot+255)/256),256,0,stream>>>(rin, UsAll+lvl[i], UdAll+lvl[i], CSM, rout, h, 12-i, (i==0)?1:0, FLAG);
    rin = (bfu*)rout;
  }
}